// Round 1
// baseline (1076.129 us; speedup 1.0000x reference)
//
#include <hip/hip_runtime.h>
#include <math.h>

#define TPB 256

// ---------------- CSR build ----------------

__global__ __launch_bounds__(TPB) void zero_cnt_k(int* __restrict__ cnt, int N) {
  int i = blockIdx.x * TPB + threadIdx.x;
  if (i < N) cnt[i] = 0;
}

__global__ __launch_bounds__(TPB) void count_k(const int* __restrict__ dstv,
                                               int* __restrict__ cnt, int E) {
  int e = blockIdx.x * TPB + threadIdx.x;
  if (e < E) atomicAdd(&cnt[dstv[e]], 1);
}

// block scans 1024 elements; writes per-element local-exclusive into excl, block total to blk_sums
__global__ __launch_bounds__(TPB) void scan1_k(const int* __restrict__ cnt,
                                               int* __restrict__ excl,
                                               int* __restrict__ blk_sums, int N) {
  __shared__ int sh[TPB];
  int b = blockIdx.x, tid = threadIdx.x;
  int base = b * 1024 + tid * 4;
  int v[4];
  int sum = 0;
#pragma unroll
  for (int j = 0; j < 4; ++j) {
    int i = base + j;
    v[j] = (i < N) ? cnt[i] : 0;
    sum += v[j];
  }
  sh[tid] = sum;
  __syncthreads();
  for (int off = 1; off < TPB; off <<= 1) {
    int t = (tid >= off) ? sh[tid - off] : 0;
    __syncthreads();
    sh[tid] += t;
    __syncthreads();
  }
  if (tid == TPB - 1) blk_sums[b] = sh[TPB - 1];
  int run = (tid > 0) ? sh[tid - 1] : 0;
#pragma unroll
  for (int j = 0; j < 4; ++j) {
    int i = base + j;
    if (i < N) excl[i] = run;
    run += v[j];
  }
}

// single block: exclusive scan of NB (<=256) block sums in place
__global__ __launch_bounds__(TPB) void scan2_k(int* __restrict__ blk_sums, int NB) {
  __shared__ int sh[TPB];
  int tid = threadIdx.x;
  sh[tid] = (tid < NB) ? blk_sums[tid] : 0;
  __syncthreads();
  for (int off = 1; off < TPB; off <<= 1) {
    int t = (tid >= off) ? sh[tid - off] : 0;
    __syncthreads();
    sh[tid] += t;
    __syncthreads();
  }
  int ex = (tid > 0) ? sh[tid - 1] : 0;
  if (tid < NB) blk_sums[tid] = ex;
}

__global__ __launch_bounds__(TPB) void finalize_k(int* __restrict__ row_ptr,
                                                  const int* __restrict__ blk_sums,
                                                  int* __restrict__ cursor,
                                                  const int* __restrict__ cnt,
                                                  float* __restrict__ dis, int N, int E) {
  int i = blockIdx.x * TPB + threadIdx.x;
  if (i < N) {
    int r = row_ptr[i] + blk_sums[i >> 10];
    row_ptr[i] = r;
    cursor[i] = r;
    dis[i] = rsqrtf((float)(cnt[i] + 1));  // +1 self-loop
  }
  if (blockIdx.x == 0 && threadIdx.x == 0) row_ptr[N] = E;
}

__global__ __launch_bounds__(TPB) void fill_k(const int* __restrict__ srcv,
                                              const int* __restrict__ dstv,
                                              int* __restrict__ cursor,
                                              int* __restrict__ col_src, int E) {
  int e = blockIdx.x * TPB + threadIdx.x;
  if (e < E) {
    int d = dstv[e];
    int pos = atomicAdd(&cursor[d], 1);
    col_src[pos] = srcv[e];
  }
}

// ---------------- f32 tiled GEMM: C[M,N] = A[M,K] @ W[K,N] ----------------
// 64x64 tile, BK=16, 256 threads, 4x4 microtile per thread.

#define BM 64
#define BN 64
#define BK 16
#define LDT 68  // padded leading dim (64+4 keeps float4 alignment, breaks bank stride)

__global__ __launch_bounds__(TPB) void gemm_f32_k(const float* __restrict__ A,
                                                  const float* __restrict__ W,
                                                  float* __restrict__ C,
                                                  int M, int N, int K) {
  __shared__ float As[BK][LDT];
  __shared__ float Bs[BK][LDT];
  int tid = threadIdx.x;
  int tx = tid & 15, ty = tid >> 4;
  int m0 = blockIdx.y * BM, n0 = blockIdx.x * BN;

  float acc[4][4];
#pragma unroll
  for (int i = 0; i < 4; ++i)
#pragma unroll
    for (int j = 0; j < 4; ++j) acc[i][j] = 0.f;

  for (int k0 = 0; k0 < K; k0 += BK) {
    // A tile 64x16: thread loads float4 along K
    {
      int r = tid >> 2;
      int c4 = (tid & 3) * 4;
      int gr = m0 + r;
      float4 v = make_float4(0.f, 0.f, 0.f, 0.f);
      if (gr < M) v = *(const float4*)(A + (size_t)gr * K + k0 + c4);
      As[c4 + 0][r] = v.x;
      As[c4 + 1][r] = v.y;
      As[c4 + 2][r] = v.z;
      As[c4 + 3][r] = v.w;
    }
    // B tile 16x64
    {
      int r = tid >> 4;
      int c4 = (tid & 15) * 4;
      float4 v = *(const float4*)(W + (size_t)(k0 + r) * N + n0 + c4);
      *(float4*)&Bs[r][c4] = v;
    }
    __syncthreads();
#pragma unroll
    for (int kk = 0; kk < BK; ++kk) {
      float4 a = *(const float4*)&As[kk][ty * 4];
      float4 b = *(const float4*)&Bs[kk][tx * 4];
      acc[0][0] = fmaf(a.x, b.x, acc[0][0]);
      acc[0][1] = fmaf(a.x, b.y, acc[0][1]);
      acc[0][2] = fmaf(a.x, b.z, acc[0][2]);
      acc[0][3] = fmaf(a.x, b.w, acc[0][3]);
      acc[1][0] = fmaf(a.y, b.x, acc[1][0]);
      acc[1][1] = fmaf(a.y, b.y, acc[1][1]);
      acc[1][2] = fmaf(a.y, b.z, acc[1][2]);
      acc[1][3] = fmaf(a.y, b.w, acc[1][3]);
      acc[2][0] = fmaf(a.z, b.x, acc[2][0]);
      acc[2][1] = fmaf(a.z, b.y, acc[2][1]);
      acc[2][2] = fmaf(a.z, b.z, acc[2][2]);
      acc[2][3] = fmaf(a.z, b.w, acc[2][3]);
      acc[3][0] = fmaf(a.w, b.x, acc[3][0]);
      acc[3][1] = fmaf(a.w, b.y, acc[3][1]);
      acc[3][2] = fmaf(a.w, b.z, acc[3][2]);
      acc[3][3] = fmaf(a.w, b.w, acc[3][3]);
    }
    __syncthreads();
  }
#pragma unroll
  for (int i = 0; i < 4; ++i) {
    int gr = m0 + ty * 4 + i;
    if (gr < M) {
      float4 o = make_float4(acc[i][0], acc[i][1], acc[i][2], acc[i][3]);
      *(float4*)(C + (size_t)gr * N + n0 + tx * 4) = o;
    }
  }
}

// ---------------- aggregation: one wave per node ----------------
// O[v] = relu( dis[v] * sum_{e:dst=v} dis[src]*H[src] + dis[v]^2 * H[v] + b )

__global__ __launch_bounds__(TPB) void aggregate_k(const float* __restrict__ H,
                                                   float* __restrict__ O,
                                                   const int* __restrict__ row_ptr,
                                                   const int* __restrict__ col_src,
                                                   const float* __restrict__ dis,
                                                   const float* __restrict__ bias,
                                                   int N) {
  int wid = (blockIdx.x * TPB + threadIdx.x) >> 6;
  int lane = threadIdx.x & 63;
  if (wid >= N) return;
  int v = wid;
  int beg = row_ptr[v], end = row_ptr[v + 1];
  float ax = 0.f, ay = 0.f, az = 0.f, aw = 0.f;
  for (int e = beg; e < end; ++e) {
    int s = col_src[e];
    float w = dis[s];
    float4 h = *(const float4*)(H + (size_t)s * 256 + lane * 4);
    ax = fmaf(w, h.x, ax);
    ay = fmaf(w, h.y, ay);
    az = fmaf(w, h.z, az);
    aw = fmaf(w, h.w, aw);
  }
  float dv = dis[v];
  float dv2 = dv * dv;
  float4 hv = *(const float4*)(H + (size_t)v * 256 + lane * 4);
  float4 b = *(const float4*)(bias + lane * 4);
  float4 o;
  o.x = fmaxf(fmaf(dv, ax, fmaf(dv2, hv.x, b.x)), 0.f);
  o.y = fmaxf(fmaf(dv, ay, fmaf(dv2, hv.y, b.y)), 0.f);
  o.z = fmaxf(fmaf(dv, az, fmaf(dv2, hv.z, b.z)), 0.f);
  o.w = fmaxf(fmaf(dv, aw, fmaf(dv2, hv.w, b.w)), 0.f);
  *(float4*)(O + (size_t)v * 256 + lane * 4) = o;
}

// ---------------- fused final layer: logits = H @ Wo + bo ; log_softmax ----------------
// Wo (256x64 = 64KB) staged in LDS. One wave per row; lane = output column.

__global__ __launch_bounds__(TPB) void out_k(const float* __restrict__ H,
                                             const float* __restrict__ Wo,
                                             const float* __restrict__ bo,
                                             float* __restrict__ out, int N) {
  __shared__ float Wl[256 * 64];
  for (int i = threadIdx.x; i < 256 * 64 / 4; i += TPB) {
    ((float4*)Wl)[i] = ((const float4*)Wo)[i];
  }
  __syncthreads();
  int lane = threadIdx.x & 63;
  int wid = threadIdx.x >> 6;  // 0..3
  float biasv = bo[lane];
  for (int v = blockIdx.x * 4 + wid; v < N; v += gridDim.x * 4) {
    const float* hrow = H + (size_t)v * 256;
    float acc = biasv;
#pragma unroll 8
    for (int k = 0; k < 256; k += 4) {
      float4 h = *(const float4*)(hrow + k);  // wave-uniform load
      acc = fmaf(h.x, Wl[(k + 0) * 64 + lane], acc);
      acc = fmaf(h.y, Wl[(k + 1) * 64 + lane], acc);
      acc = fmaf(h.z, Wl[(k + 2) * 64 + lane], acc);
      acc = fmaf(h.w, Wl[(k + 3) * 64 + lane], acc);
    }
    // log_softmax across the 64 lanes
    float m = acc;
    for (int o = 32; o > 0; o >>= 1) m = fmaxf(m, __shfl_xor(m, o, 64));
    float ex = expf(acc - m);
    float s = ex;
    for (int o = 32; o > 0; o >>= 1) s += __shfl_xor(s, o, 64);
    out[(size_t)v * 64 + lane] = (acc - m) - logf(s);
  }
}

// ---------------- launch ----------------

extern "C" void kernel_launch(void* const* d_in, const int* in_sizes, int n_in,
                              void* d_out, int out_size, void* d_ws, size_t ws_size,
                              hipStream_t stream) {
  const float* x = (const float*)d_in[0];
  const int* ei = (const int*)d_in[1];
  const float* W1 = (const float*)d_in[2];
  const float* b1 = (const float*)d_in[3];
  const float* W2 = (const float*)d_in[4];
  const float* b2 = (const float*)d_in[5];
  const float* Wo = (const float*)d_in[6];
  const float* bo = (const float*)d_in[7];
  float* out = (float*)d_out;

  const int Dh = 256;
  const int N = in_sizes[0] / Dh;
  const int E = in_sizes[1] / 2;
  const int* srcv = ei;
  const int* dstv = ei + E;

  char* p = (char*)d_ws;
  auto take = [&](size_t bytes) {
    char* r = p;
    p += (bytes + 255) & ~(size_t)255;
    return r;
  };
  float* bufA = (float*)take((size_t)N * Dh * 4);
  float* bufB = (float*)take((size_t)N * Dh * 4);
  float* dis = (float*)take((size_t)N * 4);
  int* cnt = (int*)take((size_t)N * 4);
  int* row_ptr = (int*)take((size_t)(N + 1) * 4);
  int* cursor = (int*)take((size_t)N * 4);
  int* col_src = (int*)take((size_t)E * 4);
  int* blk_sums = (int*)take(4096 * 4);

  int NB = (N + 1023) / 1024;  // 98 for N=100000 (must be <=256)

  // CSR + degrees
  zero_cnt_k<<<(N + TPB - 1) / TPB, TPB, 0, stream>>>(cnt, N);
  count_k<<<(E + TPB - 1) / TPB, TPB, 0, stream>>>(dstv, cnt, E);
  scan1_k<<<NB, TPB, 0, stream>>>(cnt, row_ptr, blk_sums, N);
  scan2_k<<<1, TPB, 0, stream>>>(blk_sums, NB);
  finalize_k<<<(N + TPB - 1) / TPB, TPB, 0, stream>>>(row_ptr, blk_sums, cursor, cnt, dis, N, E);
  fill_k<<<(E + TPB - 1) / TPB, TPB, 0, stream>>>(srcv, dstv, cursor, col_src, E);

  dim3 ggrid(256 / BN, (N + BM - 1) / BM);

  // layer 1
  gemm_f32_k<<<ggrid, TPB, 0, stream>>>(x, W1, bufA, N, 256, 256);
  aggregate_k<<<(N + 3) / 4, TPB, 0, stream>>>(bufA, bufB, row_ptr, col_src, dis, b1, N);
  // layer 2
  gemm_f32_k<<<ggrid, TPB, 0, stream>>>(bufB, W2, bufA, N, 256, 256);
  aggregate_k<<<(N + 3) / 4, TPB, 0, stream>>>(bufA, bufB, row_ptr, col_src, dis, b2, N);
  // output layer + log_softmax
  out_k<<<2048, TPB, 0, stream>>>(bufB, Wo, bo, out, N);
}

// Round 2
// 1037.176 us; speedup vs baseline: 1.0376x; 1.0376x over previous
//
#include <hip/hip_runtime.h>
#include <math.h>

#define TPB 256

// ---------------- CSR build ----------------

__global__ __launch_bounds__(TPB) void zero_cnt_k(int* __restrict__ cnt, int N) {
  int i = blockIdx.x * TPB + threadIdx.x;
  if (i < N) cnt[i] = 0;
}

__global__ __launch_bounds__(TPB) void count_k(const int* __restrict__ dstv,
                                               int* __restrict__ cnt, int E) {
  int e = blockIdx.x * TPB + threadIdx.x;
  if (e < E) atomicAdd(&cnt[dstv[e]], 1);
}

// block scans 1024 elements; writes per-element local-exclusive into excl, block total to blk_sums
__global__ __launch_bounds__(TPB) void scan1_k(const int* __restrict__ cnt,
                                               int* __restrict__ excl,
                                               int* __restrict__ blk_sums, int N) {
  __shared__ int sh[TPB];
  int b = blockIdx.x, tid = threadIdx.x;
  int base = b * 1024 + tid * 4;
  int v[4];
  int sum = 0;
#pragma unroll
  for (int j = 0; j < 4; ++j) {
    int i = base + j;
    v[j] = (i < N) ? cnt[i] : 0;
    sum += v[j];
  }
  sh[tid] = sum;
  __syncthreads();
  for (int off = 1; off < TPB; off <<= 1) {
    int t = (tid >= off) ? sh[tid - off] : 0;
    __syncthreads();
    sh[tid] += t;
    __syncthreads();
  }
  if (tid == TPB - 1) blk_sums[b] = sh[TPB - 1];
  int run = (tid > 0) ? sh[tid - 1] : 0;
#pragma unroll
  for (int j = 0; j < 4; ++j) {
    int i = base + j;
    if (i < N) excl[i] = run;
    run += v[j];
  }
}

// single block: exclusive scan of NB (<=256) block sums in place
__global__ __launch_bounds__(TPB) void scan2_k(int* __restrict__ blk_sums, int NB) {
  __shared__ int sh[TPB];
  int tid = threadIdx.x;
  sh[tid] = (tid < NB) ? blk_sums[tid] : 0;
  __syncthreads();
  for (int off = 1; off < TPB; off <<= 1) {
    int t = (tid >= off) ? sh[tid - off] : 0;
    __syncthreads();
    sh[tid] += t;
    __syncthreads();
  }
  int ex = (tid > 0) ? sh[tid - 1] : 0;
  if (tid < NB) blk_sums[tid] = ex;
}

__global__ __launch_bounds__(TPB) void finalize_k(int* __restrict__ row_ptr,
                                                  const int* __restrict__ blk_sums,
                                                  int* __restrict__ cursor,
                                                  const int* __restrict__ cnt,
                                                  float* __restrict__ dis, int N, int E) {
  int i = blockIdx.x * TPB + threadIdx.x;
  if (i < N) {
    int r = row_ptr[i] + blk_sums[i >> 10];
    row_ptr[i] = r;
    cursor[i] = r;
    dis[i] = rsqrtf((float)(cnt[i] + 1));  // +1 self-loop
  }
  if (blockIdx.x == 0 && threadIdx.x == 0) row_ptr[N] = E;
}

__global__ __launch_bounds__(TPB) void fill_k(const int* __restrict__ srcv,
                                              const int* __restrict__ dstv,
                                              int* __restrict__ cursor,
                                              int* __restrict__ col_src, int E) {
  int e = blockIdx.x * TPB + threadIdx.x;
  if (e < E) {
    int d = dstv[e];
    int pos = atomicAdd(&cursor[d], 1);
    col_src[pos] = srcv[e];
  }
}

// ---------------- f32 tiled GEMM: C[M,N] = A[M,K] @ W[K,N] ----------------
// 128x128 tile, BK=16, 256 threads, 8x8 microtile per thread.

#define GBM 128
#define GBN 128
#define GBK 16
#define LDA 132  // 128 + 4 (16B-aligned pad)
#define LDB 196  // swizzled width: col c stored at c + (c>>3)*4, max 127->187

__device__ __forceinline__ int bswz(int c) { return c + ((c >> 3) << 2); }

__global__ __launch_bounds__(TPB) void gemm_f32_k(const float* __restrict__ A,
                                                  const float* __restrict__ W,
                                                  float* __restrict__ C,
                                                  int M, int N, int K) {
  __shared__ float As[GBK][LDA];
  __shared__ float Bs[GBK][LDB];
  int tid = threadIdx.x;
  int tx = tid & 15, ty = tid >> 4;
  int m0 = blockIdx.y * GBM, n0 = blockIdx.x * GBN;

  float acc[8][8];
#pragma unroll
  for (int i = 0; i < 8; ++i)
#pragma unroll
    for (int j = 0; j < 8; ++j) acc[i][j] = 0.f;

  // staging indices
  int ar = tid >> 1;            // 0..127  (A tile row)
  int akh = (tid & 1) * 8;      // 0 or 8  (A tile k-offset)
  int bkr = tid >> 4;           // 0..15   (B tile k row)
  int bc8 = (tid & 15) * 8;     // 0..120  (B tile col base)
  int bcs = bswz(bc8);          // 12*(tid&15)

  for (int k0 = 0; k0 < K; k0 += GBK) {
    // A tile 128x16 (transposed into As[k][m])
    {
      int gr = m0 + ar;
      float4 v0 = make_float4(0.f, 0.f, 0.f, 0.f), v1 = v0;
      if (gr < M) {
        const float* ap = A + (size_t)gr * K + k0 + akh;
        v0 = *(const float4*)(ap);
        v1 = *(const float4*)(ap + 4);
      }
      As[akh + 0][ar] = v0.x;
      As[akh + 1][ar] = v0.y;
      As[akh + 2][ar] = v0.z;
      As[akh + 3][ar] = v0.w;
      As[akh + 4][ar] = v1.x;
      As[akh + 5][ar] = v1.y;
      As[akh + 6][ar] = v1.z;
      As[akh + 7][ar] = v1.w;
    }
    // B tile 16x128 (swizzled columns)
    {
      const float* wp = W + (size_t)(k0 + bkr) * N + n0 + bc8;
      float4 v0 = *(const float4*)(wp);
      float4 v1 = *(const float4*)(wp + 4);
      *(float4*)&Bs[bkr][bcs] = v0;
      *(float4*)&Bs[bkr][bcs + 4] = v1;
    }
    __syncthreads();
#pragma unroll
    for (int kk = 0; kk < GBK; ++kk) {
      float4 a0 = *(const float4*)&As[kk][ty * 8];
      float4 a1 = *(const float4*)&As[kk][ty * 8 + 4];
      float4 b0 = *(const float4*)&Bs[kk][bcs];
      float4 b1 = *(const float4*)&Bs[kk][bcs + 4];
      float av[8] = {a0.x, a0.y, a0.z, a0.w, a1.x, a1.y, a1.z, a1.w};
      float bv[8] = {b0.x, b0.y, b0.z, b0.w, b1.x, b1.y, b1.z, b1.w};
#pragma unroll
      for (int i = 0; i < 8; ++i)
#pragma unroll
        for (int j = 0; j < 8; ++j) acc[i][j] = fmaf(av[i], bv[j], acc[i][j]);
    }
    __syncthreads();
  }
#pragma unroll
  for (int i = 0; i < 8; ++i) {
    int gr = m0 + ty * 8 + i;
    if (gr < M) {
      float* cp = C + (size_t)gr * N + n0 + tx * 8;
      *(float4*)(cp) = make_float4(acc[i][0], acc[i][1], acc[i][2], acc[i][3]);
      *(float4*)(cp + 4) = make_float4(acc[i][4], acc[i][5], acc[i][6], acc[i][7]);
    }
  }
}

// ---------------- aggregation: one wave per node ----------------
// O[v] = relu( dis[v] * sum_{e:dst=v} dis[src]*H[src] + dis[v]^2 * H[v] + b )

__global__ __launch_bounds__(TPB) void aggregate_k(const float* __restrict__ H,
                                                   float* __restrict__ O,
                                                   const int* __restrict__ row_ptr,
                                                   const int* __restrict__ col_src,
                                                   const float* __restrict__ dis,
                                                   const float* __restrict__ bias,
                                                   int N) {
  int wid = (blockIdx.x * TPB + threadIdx.x) >> 6;
  int lane = threadIdx.x & 63;
  if (wid >= N) return;
  int v = wid;
  int beg = row_ptr[v], end = row_ptr[v + 1];
  float ax = 0.f, ay = 0.f, az = 0.f, aw = 0.f;
  for (int e = beg; e < end; ++e) {
    int s = col_src[e];
    float w = dis[s];
    float4 h = *(const float4*)(H + (size_t)s * 256 + lane * 4);
    ax = fmaf(w, h.x, ax);
    ay = fmaf(w, h.y, ay);
    az = fmaf(w, h.z, az);
    aw = fmaf(w, h.w, aw);
  }
  float dv = dis[v];
  float dv2 = dv * dv;
  float4 hv = *(const float4*)(H + (size_t)v * 256 + lane * 4);
  float4 b = *(const float4*)(bias + lane * 4);
  float4 o;
  o.x = fmaxf(fmaf(dv, ax, fmaf(dv2, hv.x, b.x)), 0.f);
  o.y = fmaxf(fmaf(dv, ay, fmaf(dv2, hv.y, b.y)), 0.f);
  o.z = fmaxf(fmaf(dv, az, fmaf(dv2, hv.z, b.z)), 0.f);
  o.w = fmaxf(fmaf(dv, aw, fmaf(dv2, hv.w, b.w)), 0.f);
  *(float4*)(O + (size_t)v * 256 + lane * 4) = o;
}

// ---------------- fused final layer: logits = H @ Wo + bo ; log_softmax ----------------
// Wo (256x64 = 64KB) staged in LDS. One wave handles 8 rows; lane = output column.
// Each LDS read of Wo now feeds 8 FMAs (was 1).

#define OUTR 8

__global__ __launch_bounds__(TPB) void out_k(const float* __restrict__ H,
                                             const float* __restrict__ Wo,
                                             const float* __restrict__ bo,
                                             float* __restrict__ out, int N) {
  __shared__ float Wl[256 * 64];
  for (int i = threadIdx.x; i < 256 * 64 / 4; i += TPB) {
    ((float4*)Wl)[i] = ((const float4*)Wo)[i];
  }
  __syncthreads();
  int lane = threadIdx.x & 63;
  int wid = blockIdx.x * (TPB / 64) + (threadIdx.x >> 6);
  int nw = gridDim.x * (TPB / 64);
  float biasv = bo[lane];

  for (int v0 = wid * OUTR; v0 < N; v0 += nw * OUTR) {
    float acc[OUTR];
#pragma unroll
    for (int r = 0; r < OUTR; ++r) acc[r] = biasv;
    int nr = min(OUTR, N - v0);
    if (nr == OUTR) {
      const float* hp = H + (size_t)v0 * 256;
      for (int k = 0; k < 256; k += 4) {
        float w0 = Wl[(k + 0) * 64 + lane];
        float w1 = Wl[(k + 1) * 64 + lane];
        float w2 = Wl[(k + 2) * 64 + lane];
        float w3 = Wl[(k + 3) * 64 + lane];
#pragma unroll
        for (int r = 0; r < OUTR; ++r) {
          float4 h = *(const float4*)(hp + (size_t)r * 256 + k);  // wave-uniform
          acc[r] = fmaf(h.x, w0, acc[r]);
          acc[r] = fmaf(h.y, w1, acc[r]);
          acc[r] = fmaf(h.z, w2, acc[r]);
          acc[r] = fmaf(h.w, w3, acc[r]);
        }
      }
    } else {
      for (int k = 0; k < 256; k += 4) {
        float w0 = Wl[(k + 0) * 64 + lane];
        float w1 = Wl[(k + 1) * 64 + lane];
        float w2 = Wl[(k + 2) * 64 + lane];
        float w3 = Wl[(k + 3) * 64 + lane];
        for (int r = 0; r < nr; ++r) {
          float4 h = *(const float4*)(H + (size_t)(v0 + r) * 256 + k);
          acc[r] = fmaf(h.x, w0, acc[r]);
          acc[r] = fmaf(h.y, w1, acc[r]);
          acc[r] = fmaf(h.z, w2, acc[r]);
          acc[r] = fmaf(h.w, w3, acc[r]);
        }
      }
    }
    for (int r = 0; r < nr; ++r) {
      float a = acc[r];
      float m = a;
      for (int o = 32; o > 0; o >>= 1) m = fmaxf(m, __shfl_xor(m, o, 64));
      float ex = expf(a - m);
      float s = ex;
      for (int o = 32; o > 0; o >>= 1) s += __shfl_xor(s, o, 64);
      out[(size_t)(v0 + r) * 64 + lane] = (a - m) - logf(s);
    }
  }
}

// ---------------- launch ----------------

extern "C" void kernel_launch(void* const* d_in, const int* in_sizes, int n_in,
                              void* d_out, int out_size, void* d_ws, size_t ws_size,
                              hipStream_t stream) {
  const float* x = (const float*)d_in[0];
  const int* ei = (const int*)d_in[1];
  const float* W1 = (const float*)d_in[2];
  const float* b1 = (const float*)d_in[3];
  const float* W2 = (const float*)d_in[4];
  const float* b2 = (const float*)d_in[5];
  const float* Wo = (const float*)d_in[6];
  const float* bo = (const float*)d_in[7];
  float* out = (float*)d_out;

  const int Dh = 256;
  const int N = in_sizes[0] / Dh;
  const int E = in_sizes[1] / 2;
  const int* srcv = ei;
  const int* dstv = ei + E;

  char* p = (char*)d_ws;
  auto take = [&](size_t bytes) {
    char* r = p;
    p += (bytes + 255) & ~(size_t)255;
    return r;
  };
  float* bufA = (float*)take((size_t)N * Dh * 4);
  float* bufB = (float*)take((size_t)N * Dh * 4);
  float* dis = (float*)take((size_t)N * 4);
  int* cnt = (int*)take((size_t)N * 4);
  int* row_ptr = (int*)take((size_t)(N + 1) * 4);
  int* cursor = (int*)take((size_t)N * 4);
  int* col_src = (int*)take((size_t)E * 4);
  int* blk_sums = (int*)take(4096 * 4);

  int NB = (N + 1023) / 1024;  // 98 for N=100000 (must be <=256)

  // CSR + degrees
  zero_cnt_k<<<(N + TPB - 1) / TPB, TPB, 0, stream>>>(cnt, N);
  count_k<<<(E + TPB - 1) / TPB, TPB, 0, stream>>>(dstv, cnt, E);
  scan1_k<<<NB, TPB, 0, stream>>>(cnt, row_ptr, blk_sums, N);
  scan2_k<<<1, TPB, 0, stream>>>(blk_sums, NB);
  finalize_k<<<(N + TPB - 1) / TPB, TPB, 0, stream>>>(row_ptr, blk_sums, cursor, cnt, dis, N, E);
  fill_k<<<(E + TPB - 1) / TPB, TPB, 0, stream>>>(srcv, dstv, cursor, col_src, E);

  dim3 ggrid(256 / GBN, (N + GBM - 1) / GBM);

  // layer 1
  gemm_f32_k<<<ggrid, TPB, 0, stream>>>(x, W1, bufA, N, 256, 256);
  aggregate_k<<<(N + 3) / 4, TPB, 0, stream>>>(bufA, bufB, row_ptr, col_src, dis, b1, N);
  // layer 2
  gemm_f32_k<<<ggrid, TPB, 0, stream>>>(bufB, W2, bufA, N, 256, 256);
  aggregate_k<<<(N + 3) / 4, TPB, 0, stream>>>(bufA, bufB, row_ptr, col_src, dis, b2, N);
  // output layer + log_softmax
  out_k<<<2048, TPB, 0, stream>>>(bufB, Wo, bo, out, N);
}

// Round 3
// 923.002 us; speedup vs baseline: 1.1659x; 1.1237x over previous
//
#include <hip/hip_runtime.h>
#include <math.h>

#define TPB 256

// ---------------- CSR build ----------------

__global__ __launch_bounds__(TPB) void zero_cnt_k(int* __restrict__ cnt, int N) {
  int i = blockIdx.x * TPB + threadIdx.x;
  if (i < N) cnt[i] = 0;
}

__global__ __launch_bounds__(TPB) void count_k(const int* __restrict__ dstv,
                                               int* __restrict__ cnt, int E) {
  int e = blockIdx.x * TPB + threadIdx.x;
  if (e < E) atomicAdd(&cnt[dstv[e]], 1);
}

// block scans 1024 elements; writes per-element local-exclusive into excl, block total to blk_sums
__global__ __launch_bounds__(TPB) void scan1_k(const int* __restrict__ cnt,
                                               int* __restrict__ excl,
                                               int* __restrict__ blk_sums, int N) {
  __shared__ int sh[TPB];
  int b = blockIdx.x, tid = threadIdx.x;
  int base = b * 1024 + tid * 4;
  int v[4];
  int sum = 0;
#pragma unroll
  for (int j = 0; j < 4; ++j) {
    int i = base + j;
    v[j] = (i < N) ? cnt[i] : 0;
    sum += v[j];
  }
  sh[tid] = sum;
  __syncthreads();
  for (int off = 1; off < TPB; off <<= 1) {
    int t = (tid >= off) ? sh[tid - off] : 0;
    __syncthreads();
    sh[tid] += t;
    __syncthreads();
  }
  if (tid == TPB - 1) blk_sums[b] = sh[TPB - 1];
  int run = (tid > 0) ? sh[tid - 1] : 0;
#pragma unroll
  for (int j = 0; j < 4; ++j) {
    int i = base + j;
    if (i < N) excl[i] = run;
    run += v[j];
  }
}

// single block: exclusive scan of NB (<=256) block sums in place
__global__ __launch_bounds__(TPB) void scan2_k(int* __restrict__ blk_sums, int NB) {
  __shared__ int sh[TPB];
  int tid = threadIdx.x;
  sh[tid] = (tid < NB) ? blk_sums[tid] : 0;
  __syncthreads();
  for (int off = 1; off < TPB; off <<= 1) {
    int t = (tid >= off) ? sh[tid - off] : 0;
    __syncthreads();
    sh[tid] += t;
    __syncthreads();
  }
  int ex = (tid > 0) ? sh[tid - 1] : 0;
  if (tid < NB) blk_sums[tid] = ex;
}

__global__ __launch_bounds__(TPB) void finalize_k(int* __restrict__ row_ptr,
                                                  const int* __restrict__ blk_sums,
                                                  int* __restrict__ cursor,
                                                  const int* __restrict__ cnt,
                                                  float* __restrict__ dis, int N, int E) {
  int i = blockIdx.x * TPB + threadIdx.x;
  if (i < N) {
    int r = row_ptr[i] + blk_sums[i >> 10];
    row_ptr[i] = r;
    cursor[i] = r;
    dis[i] = rsqrtf((float)(cnt[i] + 1));  // +1 self-loop
  }
  if (blockIdx.x == 0 && threadIdx.x == 0) row_ptr[N] = E;
}

__global__ __launch_bounds__(TPB) void fill_k(const int* __restrict__ srcv,
                                              const int* __restrict__ dstv,
                                              int* __restrict__ cursor,
                                              int* __restrict__ col_src, int E) {
  int e = blockIdx.x * TPB + threadIdx.x;
  if (e < E) {
    int d = dstv[e];
    int pos = atomicAdd(&cursor[d], 1);
    col_src[pos] = srcv[e];
  }
}

// ---------------- f32 tiled GEMM: C[M,N] = A[M,K] @ W[K,N] ----------------
// 128x128 tile, BK=16, 256 threads, 8x8 microtile per thread.

#define GBM 128
#define GBN 128
#define GBK 16
#define LDA 132  // 128 + 4 (16B-aligned pad)
#define LDB 196  // swizzled width: col c stored at c + (c>>3)*4, max 127->187

__device__ __forceinline__ int bswz(int c) { return c + ((c >> 3) << 2); }

__global__ __launch_bounds__(TPB) void gemm_f32_k(const float* __restrict__ A,
                                                  const float* __restrict__ W,
                                                  float* __restrict__ C,
                                                  int M, int N, int K) {
  __shared__ float As[GBK][LDA];
  __shared__ float Bs[GBK][LDB];
  int tid = threadIdx.x;
  int tx = tid & 15, ty = tid >> 4;
  int m0 = blockIdx.y * GBM, n0 = blockIdx.x * GBN;

  float acc[8][8];
#pragma unroll
  for (int i = 0; i < 8; ++i)
#pragma unroll
    for (int j = 0; j < 8; ++j) acc[i][j] = 0.f;

  // staging indices
  int ar = tid >> 1;            // 0..127  (A tile row)
  int akh = (tid & 1) * 8;      // 0 or 8  (A tile k-offset)
  int bkr = tid >> 4;           // 0..15   (B tile k row)
  int bc8 = (tid & 15) * 8;     // 0..120  (B tile col base)
  int bcs = bswz(bc8);          // 12*(tid&15)

  for (int k0 = 0; k0 < K; k0 += GBK) {
    // A tile 128x16 (transposed into As[k][m])
    {
      int gr = m0 + ar;
      float4 v0 = make_float4(0.f, 0.f, 0.f, 0.f), v1 = v0;
      if (gr < M) {
        const float* ap = A + (size_t)gr * K + k0 + akh;
        v0 = *(const float4*)(ap);
        v1 = *(const float4*)(ap + 4);
      }
      As[akh + 0][ar] = v0.x;
      As[akh + 1][ar] = v0.y;
      As[akh + 2][ar] = v0.z;
      As[akh + 3][ar] = v0.w;
      As[akh + 4][ar] = v1.x;
      As[akh + 5][ar] = v1.y;
      As[akh + 6][ar] = v1.z;
      As[akh + 7][ar] = v1.w;
    }
    // B tile 16x128 (swizzled columns)
    {
      const float* wp = W + (size_t)(k0 + bkr) * N + n0 + bc8;
      float4 v0 = *(const float4*)(wp);
      float4 v1 = *(const float4*)(wp + 4);
      *(float4*)&Bs[bkr][bcs] = v0;
      *(float4*)&Bs[bkr][bcs + 4] = v1;
    }
    __syncthreads();
#pragma unroll
    for (int kk = 0; kk < GBK; ++kk) {
      float4 a0 = *(const float4*)&As[kk][ty * 8];
      float4 a1 = *(const float4*)&As[kk][ty * 8 + 4];
      float4 b0 = *(const float4*)&Bs[kk][bcs];
      float4 b1 = *(const float4*)&Bs[kk][bcs + 4];
      float av[8] = {a0.x, a0.y, a0.z, a0.w, a1.x, a1.y, a1.z, a1.w};
      float bv[8] = {b0.x, b0.y, b0.z, b0.w, b1.x, b1.y, b1.z, b1.w};
#pragma unroll
      for (int i = 0; i < 8; ++i)
#pragma unroll
        for (int j = 0; j < 8; ++j) acc[i][j] = fmaf(av[i], bv[j], acc[i][j]);
    }
    __syncthreads();
  }
#pragma unroll
  for (int i = 0; i < 8; ++i) {
    int gr = m0 + ty * 8 + i;
    if (gr < M) {
      float* cp = C + (size_t)gr * N + n0 + tx * 8;
      *(float4*)(cp) = make_float4(acc[i][0], acc[i][1], acc[i][2], acc[i][3]);
      *(float4*)(cp + 4) = make_float4(acc[i][4], acc[i][5], acc[i][6], acc[i][7]);
    }
  }
}

// ---------------- aggregation: one wave per node ----------------
// O[v] = relu( dis[v] * sum_{e:dst=v} dis[src]*H[src] + dis[v]^2 * H[v] + b )

__global__ __launch_bounds__(TPB) void aggregate_k(const float* __restrict__ H,
                                                   float* __restrict__ O,
                                                   const int* __restrict__ row_ptr,
                                                   const int* __restrict__ col_src,
                                                   const float* __restrict__ dis,
                                                   const float* __restrict__ bias,
                                                   int N) {
  int wid = (blockIdx.x * TPB + threadIdx.x) >> 6;
  int lane = threadIdx.x & 63;
  if (wid >= N) return;
  int v = wid;
  int beg = row_ptr[v], end = row_ptr[v + 1];
  float ax = 0.f, ay = 0.f, az = 0.f, aw = 0.f;
  for (int e = beg; e < end; ++e) {
    int s = col_src[e];
    float w = dis[s];
    float4 h = *(const float4*)(H + (size_t)s * 256 + lane * 4);
    ax = fmaf(w, h.x, ax);
    ay = fmaf(w, h.y, ay);
    az = fmaf(w, h.z, az);
    aw = fmaf(w, h.w, aw);
  }
  float dv = dis[v];
  float dv2 = dv * dv;
  float4 hv = *(const float4*)(H + (size_t)v * 256 + lane * 4);
  float4 b = *(const float4*)(bias + lane * 4);
  float4 o;
  o.x = fmaxf(fmaf(dv, ax, fmaf(dv2, hv.x, b.x)), 0.f);
  o.y = fmaxf(fmaf(dv, ay, fmaf(dv2, hv.y, b.y)), 0.f);
  o.z = fmaxf(fmaf(dv, az, fmaf(dv2, hv.z, b.z)), 0.f);
  o.w = fmaxf(fmaf(dv, aw, fmaf(dv2, hv.w, b.w)), 0.f);
  *(float4*)(O + (size_t)v * 256 + lane * 4) = o;
}

// ---------------- fused final layer: logits = H @ Wo + bo ; log_softmax ----------------
// Proper tiled skinny GEMM: 128x64 tile, 256 threads, 4x8 microtile, then
// log_softmax via an LDS logits tile (wave per row, lane = column).

#define OBM 128
#define OBK 16
#define OLDA 132
#define OLDB 72
#define OLDL 65

__global__ __launch_bounds__(TPB) void outgemm_k(const float* __restrict__ H,
                                                 const float* __restrict__ Wo,
                                                 const float* __restrict__ bo,
                                                 float* __restrict__ out, int M) {
  __shared__ float As[OBK][OLDA];
  __shared__ float Bs[OBK][OLDB];
  __shared__ float Ls[OBM][OLDL];
  int tid = threadIdx.x;
  int tx = tid & 7;    // 8 col-groups of 8
  int ty = tid >> 3;   // 32 row-groups of 4
  int m0 = blockIdx.x * OBM;

  float4 bi0 = *(const float4*)(bo + tx * 8);
  float4 bi1 = *(const float4*)(bo + tx * 8 + 4);
  float acc[4][8];
#pragma unroll
  for (int i = 0; i < 4; ++i) {
    acc[i][0] = bi0.x; acc[i][1] = bi0.y; acc[i][2] = bi0.z; acc[i][3] = bi0.w;
    acc[i][4] = bi1.x; acc[i][5] = bi1.y; acc[i][6] = bi1.z; acc[i][7] = bi1.w;
  }

  int ar = tid >> 1;        // 0..127
  int akh = (tid & 1) * 8;  // 0 or 8
  int br = tid >> 4;        // 0..15
  int bc4 = (tid & 15) * 4; // 0..60

  for (int k0 = 0; k0 < 256; k0 += OBK) {
    // A tile 128x16 -> As[k][m]
    {
      int gr = m0 + ar;
      float4 v0 = make_float4(0.f, 0.f, 0.f, 0.f), v1 = v0;
      if (gr < M) {
        const float* ap = H + (size_t)gr * 256 + k0 + akh;
        v0 = *(const float4*)(ap);
        v1 = *(const float4*)(ap + 4);
      }
      As[akh + 0][ar] = v0.x;
      As[akh + 1][ar] = v0.y;
      As[akh + 2][ar] = v0.z;
      As[akh + 3][ar] = v0.w;
      As[akh + 4][ar] = v1.x;
      As[akh + 5][ar] = v1.y;
      As[akh + 6][ar] = v1.z;
      As[akh + 7][ar] = v1.w;
    }
    // B tile 16x64 (Wo rows k0..k0+15)
    {
      *(float4*)&Bs[br][bc4] = *(const float4*)(Wo + (size_t)(k0 + br) * 64 + bc4);
    }
    __syncthreads();
#pragma unroll
    for (int kk = 0; kk < OBK; ++kk) {
      float4 a = *(const float4*)&As[kk][ty * 4];
      float4 b0 = *(const float4*)&Bs[kk][tx * 8];
      float4 b1 = *(const float4*)&Bs[kk][tx * 8 + 4];
      float av[4] = {a.x, a.y, a.z, a.w};
      float bv[8] = {b0.x, b0.y, b0.z, b0.w, b1.x, b1.y, b1.z, b1.w};
#pragma unroll
      for (int i = 0; i < 4; ++i)
#pragma unroll
        for (int j = 0; j < 8; ++j) acc[i][j] = fmaf(av[i], bv[j], acc[i][j]);
    }
    __syncthreads();
  }

  // logits -> LDS
#pragma unroll
  for (int i = 0; i < 4; ++i) {
    int r = ty * 4 + i;
    *(float4*)&Ls[r][tx * 8] = make_float4(acc[i][0], acc[i][1], acc[i][2], acc[i][3]);
    *(float4*)&Ls[r][tx * 8 + 4] = make_float4(acc[i][4], acc[i][5], acc[i][6], acc[i][7]);
  }
  __syncthreads();

  // log_softmax: wave per row, lane = column
  int lane = tid & 63;
  int w = tid >> 6;  // 0..3
  for (int r = w * 32; r < w * 32 + 32; ++r) {
    int grow = m0 + r;
    if (grow >= M) break;
    float v = Ls[r][lane];
    float mx = v;
    for (int o = 32; o > 0; o >>= 1) mx = fmaxf(mx, __shfl_xor(mx, o, 64));
    float ex = expf(v - mx);
    float s = ex;
    for (int o = 32; o > 0; o >>= 1) s += __shfl_xor(s, o, 64);
    out[(size_t)grow * 64 + lane] = (v - mx) - logf(s);
  }
}

// ---------------- launch ----------------

extern "C" void kernel_launch(void* const* d_in, const int* in_sizes, int n_in,
                              void* d_out, int out_size, void* d_ws, size_t ws_size,
                              hipStream_t stream) {
  const float* x = (const float*)d_in[0];
  const int* ei = (const int*)d_in[1];
  const float* W1 = (const float*)d_in[2];
  const float* b1 = (const float*)d_in[3];
  const float* W2 = (const float*)d_in[4];
  const float* b2 = (const float*)d_in[5];
  const float* Wo = (const float*)d_in[6];
  const float* bo = (const float*)d_in[7];
  float* out = (float*)d_out;

  const int Dh = 256;
  const int N = in_sizes[0] / Dh;
  const int E = in_sizes[1] / 2;
  const int* srcv = ei;
  const int* dstv = ei + E;

  char* p = (char*)d_ws;
  auto take = [&](size_t bytes) {
    char* r = p;
    p += (bytes + 255) & ~(size_t)255;
    return r;
  };
  float* bufA = (float*)take((size_t)N * Dh * 4);
  float* bufB = (float*)take((size_t)N * Dh * 4);
  float* dis = (float*)take((size_t)N * 4);
  int* cnt = (int*)take((size_t)N * 4);
  int* row_ptr = (int*)take((size_t)(N + 1) * 4);
  int* cursor = (int*)take((size_t)N * 4);
  int* col_src = (int*)take((size_t)E * 4);
  int* blk_sums = (int*)take(4096 * 4);

  int NB = (N + 1023) / 1024;  // 98 for N=100000 (must be <=256)

  // CSR + degrees
  zero_cnt_k<<<(N + TPB - 1) / TPB, TPB, 0, stream>>>(cnt, N);
  count_k<<<(E + TPB - 1) / TPB, TPB, 0, stream>>>(dstv, cnt, E);
  scan1_k<<<NB, TPB, 0, stream>>>(cnt, row_ptr, blk_sums, N);
  scan2_k<<<1, TPB, 0, stream>>>(blk_sums, NB);
  finalize_k<<<(N + TPB - 1) / TPB, TPB, 0, stream>>>(row_ptr, blk_sums, cursor, cnt, dis, N, E);
  fill_k<<<(E + TPB - 1) / TPB, TPB, 0, stream>>>(srcv, dstv, cursor, col_src, E);

  dim3 ggrid(256 / GBN, (N + GBM - 1) / GBM);

  // layer 1
  gemm_f32_k<<<ggrid, TPB, 0, stream>>>(x, W1, bufA, N, 256, 256);
  aggregate_k<<<(N + 3) / 4, TPB, 0, stream>>>(bufA, bufB, row_ptr, col_src, dis, b1, N);
  // layer 2
  gemm_f32_k<<<ggrid, TPB, 0, stream>>>(bufB, W2, bufA, N, 256, 256);
  aggregate_k<<<(N + 3) / 4, TPB, 0, stream>>>(bufA, bufB, row_ptr, col_src, dis, b2, N);
  // output layer + fused log_softmax
  outgemm_k<<<(N + OBM - 1) / OBM, TPB, 0, stream>>>(bufB, Wo, bo, out, N);
}

// Round 4
// 621.635 us; speedup vs baseline: 1.7311x; 1.4848x over previous
//
#include <hip/hip_runtime.h>
#include <math.h>

#define TPB 256

typedef short bf16x8 __attribute__((ext_vector_type(8)));
typedef unsigned short u16x8 __attribute__((ext_vector_type(8)));
typedef float f32x4 __attribute__((ext_vector_type(4)));

__device__ __forceinline__ float bf2f(unsigned short u) {
  union { unsigned int i; float f; } c;
  c.i = ((unsigned int)u) << 16;
  return c.f;
}
__device__ __forceinline__ unsigned short f2bf(float f) {
  union { float f; unsigned int i; } c;
  c.f = f;
  unsigned int r = c.i + 0x7FFFu + ((c.i >> 16) & 1u);
  return (unsigned short)(r >> 16);
}

// ---------------- CSR build ----------------

__global__ __launch_bounds__(TPB) void zero_cnt_k(int* __restrict__ cnt, int N) {
  int i = blockIdx.x * TPB + threadIdx.x;
  if (i < N) cnt[i] = 0;
}

__global__ __launch_bounds__(TPB) void count_k(const int* __restrict__ dstv,
                                               int* __restrict__ cnt, int E) {
  int e = blockIdx.x * TPB + threadIdx.x;
  if (e < E) atomicAdd(&cnt[dstv[e]], 1);
}

__global__ __launch_bounds__(TPB) void scan1_k(const int* __restrict__ cnt,
                                               int* __restrict__ excl,
                                               int* __restrict__ blk_sums, int N) {
  __shared__ int sh[TPB];
  int b = blockIdx.x, tid = threadIdx.x;
  int base = b * 1024 + tid * 4;
  int v[4];
  int sum = 0;
#pragma unroll
  for (int j = 0; j < 4; ++j) {
    int i = base + j;
    v[j] = (i < N) ? cnt[i] : 0;
    sum += v[j];
  }
  sh[tid] = sum;
  __syncthreads();
  for (int off = 1; off < TPB; off <<= 1) {
    int t = (tid >= off) ? sh[tid - off] : 0;
    __syncthreads();
    sh[tid] += t;
    __syncthreads();
  }
  if (tid == TPB - 1) blk_sums[b] = sh[TPB - 1];
  int run = (tid > 0) ? sh[tid - 1] : 0;
#pragma unroll
  for (int j = 0; j < 4; ++j) {
    int i = base + j;
    if (i < N) excl[i] = run;
    run += v[j];
  }
}

__global__ __launch_bounds__(TPB) void scan2_k(int* __restrict__ blk_sums, int NB) {
  __shared__ int sh[TPB];
  int tid = threadIdx.x;
  sh[tid] = (tid < NB) ? blk_sums[tid] : 0;
  __syncthreads();
  for (int off = 1; off < TPB; off <<= 1) {
    int t = (tid >= off) ? sh[tid - off] : 0;
    __syncthreads();
    sh[tid] += t;
    __syncthreads();
  }
  int ex = (tid > 0) ? sh[tid - 1] : 0;
  if (tid < NB) blk_sums[tid] = ex;
}

__global__ __launch_bounds__(TPB) void finalize_k(int* __restrict__ row_ptr,
                                                  const int* __restrict__ blk_sums,
                                                  int* __restrict__ cursor,
                                                  const int* __restrict__ cnt,
                                                  float* __restrict__ dis, int N, int E) {
  int i = blockIdx.x * TPB + threadIdx.x;
  if (i < N) {
    int r = row_ptr[i] + blk_sums[i >> 10];
    row_ptr[i] = r;
    cursor[i] = r;
    dis[i] = rsqrtf((float)(cnt[i] + 1));
  }
  if (blockIdx.x == 0 && threadIdx.x == 0) row_ptr[N] = E;
}

__global__ __launch_bounds__(TPB) void fill_k(const int* __restrict__ srcv,
                                              const int* __restrict__ dstv,
                                              int* __restrict__ cursor,
                                              int* __restrict__ col_src, int E) {
  int e = blockIdx.x * TPB + threadIdx.x;
  if (e < E) {
    int d = dstv[e];
    int pos = atomicAdd(&cursor[d], 1);
    col_src[pos] = srcv[e];
  }
}

// ---------------- conversions ----------------

// f32 -> bf16, 8 elems/thread, n must be divisible by 8
__global__ __launch_bounds__(TPB) void cvt_bf16_k(const float* __restrict__ in,
                                                  unsigned short* __restrict__ out,
                                                  long n) {
  long i = ((long)blockIdx.x * TPB + threadIdx.x) * 8;
  if (i >= n) return;
  float4 a = *(const float4*)(in + i);
  float4 b = *(const float4*)(in + i + 4);
  ushort4 o0, o1;
  o0.x = f2bf(a.x); o0.y = f2bf(a.y); o0.z = f2bf(a.z); o0.w = f2bf(a.w);
  o1.x = f2bf(b.x); o1.y = f2bf(b.y); o1.z = f2bf(b.z); o1.w = f2bf(b.w);
  *(ushort4*)(out + i) = o0;
  *(ushort4*)(out + i + 4) = o1;
}

// Wt[n][k] = bf16(W[k][n]) for 256x256 weights
__global__ __launch_bounds__(TPB) void wt_k(const float* __restrict__ W,
                                            unsigned short* __restrict__ Wt) {
  int idx = blockIdx.x * TPB + threadIdx.x;  // 65536 total
  int n = idx >> 8, k = idx & 255;
  Wt[n * 256 + k] = f2bf(W[k * 256 + n]);
}

// ---------------- bf16 MFMA GEMM: C[M,256] = A[M,256] @ Bt^T ----------------
// Bt is [n][k] (pre-transposed weight). 128x128 tile, BK=32, 4 waves,
// each wave computes 64x64 via 4x4 frags of 16x16x32 MFMA.
// LDS tiles [row][64B] with XOR swizzle byte ^= (((row>>1)&3)<<4).

__global__ __launch_bounds__(TPB) void gemm_bf16_k(const unsigned short* __restrict__ A,
                                                   const unsigned short* __restrict__ Bt,
                                                   unsigned short* __restrict__ C,
                                                   int M) {
  __shared__ unsigned short As[128 * 32];
  __shared__ unsigned short Bs[128 * 32];
  const int tid = threadIdx.x;
  const int m0 = blockIdx.y * 128;
  const int n0 = blockIdx.x * 128;
  const int lane = tid & 63;
  const int wid = tid >> 6;
  const int wr = (wid >> 1) * 64;
  const int wc = (wid & 1) * 64;

  // staging: thread covers row=tid>>1, two 16B chunks (half=tid&1)
  const int srow = tid >> 1;
  const int scb0 = (tid & 1) * 2;
  const int grow = min(m0 + srow, M - 1);
  const unsigned short* gA = A + (size_t)grow * 256 + scb0 * 8;
  const unsigned short* gB = Bt + (size_t)(n0 + srow) * 256 + scb0 * 8;
  const int swz = (srow >> 1) & 3;
  const int ls0 = srow * 64 + ((scb0 ^ swz) << 4);
  const int ls1 = srow * 64 + (((scb0 + 1) ^ swz) << 4);

  // frag read params
  const int r15 = lane & 15;
  const int cq = lane >> 4;
  const int swzr = (r15 >> 1) & 3;
  const int coff = ((cq ^ swzr) << 4);

  f32x4 acc[4][4];
#pragma unroll
  for (int i = 0; i < 4; ++i)
#pragma unroll
    for (int j = 0; j < 4; ++j)
#pragma unroll
      for (int r = 0; r < 4; ++r) acc[i][j][r] = 0.f;

  // prologue: load tile 0 staging regs
  u16x8 ra0 = *(const u16x8*)(gA);
  u16x8 ra1 = *(const u16x8*)(gA + 8);
  u16x8 rb0 = *(const u16x8*)(gB);
  u16x8 rb1 = *(const u16x8*)(gB + 8);

  for (int kt = 0; kt < 8; ++kt) {
    __syncthreads();  // LDS free (prev compute done)
    *(u16x8*)((char*)As + ls0) = ra0;
    *(u16x8*)((char*)As + ls1) = ra1;
    *(u16x8*)((char*)Bs + ls0) = rb0;
    *(u16x8*)((char*)Bs + ls1) = rb1;
    __syncthreads();  // tile ready
    if (kt < 7) {  // prefetch next tile (overlaps with MFMA below)
      ra0 = *(const u16x8*)(gA + (kt + 1) * 32);
      ra1 = *(const u16x8*)(gA + (kt + 1) * 32 + 8);
      rb0 = *(const u16x8*)(gB + (kt + 1) * 32);
      rb1 = *(const u16x8*)(gB + (kt + 1) * 32 + 8);
    }
    bf16x8 af[4], bfr[4];
#pragma unroll
    for (int i = 0; i < 4; ++i)
      af[i] = *(const bf16x8*)((char*)As + (wr + i * 16 + r15) * 64 + coff);
#pragma unroll
    for (int j = 0; j < 4; ++j)
      bfr[j] = *(const bf16x8*)((char*)Bs + (wc + j * 16 + r15) * 64 + coff);
#pragma unroll
    for (int i = 0; i < 4; ++i)
#pragma unroll
      for (int j = 0; j < 4; ++j)
        acc[i][j] = __builtin_amdgcn_mfma_f32_16x16x32_bf16(af[i], bfr[j], acc[i][j], 0, 0, 0);
  }

  // epilogue: C row = m0+wr+i*16+(lane>>4)*4+r, col = n0+wc+j*16+(lane&15)
#pragma unroll
  for (int i = 0; i < 4; ++i) {
#pragma unroll
    for (int r = 0; r < 4; ++r) {
      int row = m0 + wr + i * 16 + (lane >> 4) * 4 + r;
      if (row < M) {
#pragma unroll
        for (int j = 0; j < 4; ++j) {
          C[(size_t)row * 256 + n0 + wc + j * 16 + r15] = f2bf(acc[i][j][r]);
        }
      }
    }
  }
}

// ---------------- aggregation (bf16 H): one wave per node ----------------
// O[v] = relu( dis[v]*sum dis[s]*H[s] + dis[v]^2*H[v] + b ), bf16 in/out, f32 accum

__global__ __launch_bounds__(TPB) void aggregate_bf_k(const unsigned short* __restrict__ H,
                                                      unsigned short* __restrict__ O,
                                                      const int* __restrict__ row_ptr,
                                                      const int* __restrict__ col_src,
                                                      const float* __restrict__ dis,
                                                      const float* __restrict__ bias,
                                                      int N) {
  int wid = (blockIdx.x * TPB + threadIdx.x) >> 6;
  int lane = threadIdx.x & 63;
  if (wid >= N) return;
  int beg = row_ptr[wid], end = row_ptr[wid + 1];
  float a0 = 0.f, a1 = 0.f, a2 = 0.f, a3 = 0.f;
  for (int e = beg; e < end; ++e) {
    int s = col_src[e];
    float w = dis[s];
    ushort4 h = *(const ushort4*)(H + (size_t)s * 256 + lane * 4);
    a0 = fmaf(w, bf2f(h.x), a0);
    a1 = fmaf(w, bf2f(h.y), a1);
    a2 = fmaf(w, bf2f(h.z), a2);
    a3 = fmaf(w, bf2f(h.w), a3);
  }
  float dv = dis[wid];
  float dv2 = dv * dv;
  ushort4 hv = *(const ushort4*)(H + (size_t)wid * 256 + lane * 4);
  float4 b = *(const float4*)(bias + lane * 4);
  ushort4 o;
  o.x = f2bf(fmaxf(fmaf(dv, a0, fmaf(dv2, bf2f(hv.x), b.x)), 0.f));
  o.y = f2bf(fmaxf(fmaf(dv, a1, fmaf(dv2, bf2f(hv.y), b.y)), 0.f));
  o.z = f2bf(fmaxf(fmaf(dv, a2, fmaf(dv2, bf2f(hv.z), b.z)), 0.f));
  o.w = f2bf(fmaxf(fmaf(dv, a3, fmaf(dv2, bf2f(hv.w), b.w)), 0.f));
  *(ushort4*)(O + (size_t)wid * 256 + lane * 4) = o;
}

// ---------------- fused final layer (bf16 H): logits = H @ Wo + bo ; log_softmax ----

#define OBM 128
#define OBK 16
#define OLDA 132
#define OLDB 72
#define OLDL 65

__global__ __launch_bounds__(TPB) void outgemm_k(const unsigned short* __restrict__ H,
                                                 const float* __restrict__ Wo,
                                                 const float* __restrict__ bo,
                                                 float* __restrict__ out, int M) {
  __shared__ float As[OBK][OLDA];
  __shared__ float Bs[OBK][OLDB];
  __shared__ float Ls[OBM][OLDL];
  int tid = threadIdx.x;
  int tx = tid & 7;
  int ty = tid >> 3;
  int m0 = blockIdx.x * OBM;

  float4 bi0 = *(const float4*)(bo + tx * 8);
  float4 bi1 = *(const float4*)(bo + tx * 8 + 4);
  float acc[4][8];
#pragma unroll
  for (int i = 0; i < 4; ++i) {
    acc[i][0] = bi0.x; acc[i][1] = bi0.y; acc[i][2] = bi0.z; acc[i][3] = bi0.w;
    acc[i][4] = bi1.x; acc[i][5] = bi1.y; acc[i][6] = bi1.z; acc[i][7] = bi1.w;
  }

  int ar = tid >> 1;
  int akh = (tid & 1) * 8;
  int br = tid >> 4;
  int bc4 = (tid & 15) * 4;

  for (int k0 = 0; k0 < 256; k0 += OBK) {
    {
      int gr = m0 + ar;
      if (gr < M) {
        u16x8 v = *(const u16x8*)(H + (size_t)gr * 256 + k0 + akh);
        As[akh + 0][ar] = bf2f(v[0]);
        As[akh + 1][ar] = bf2f(v[1]);
        As[akh + 2][ar] = bf2f(v[2]);
        As[akh + 3][ar] = bf2f(v[3]);
        As[akh + 4][ar] = bf2f(v[4]);
        As[akh + 5][ar] = bf2f(v[5]);
        As[akh + 6][ar] = bf2f(v[6]);
        As[akh + 7][ar] = bf2f(v[7]);
      } else {
#pragma unroll
        for (int j = 0; j < 8; ++j) As[akh + j][ar] = 0.f;
      }
    }
    *(float4*)&Bs[br][bc4] = *(const float4*)(Wo + (size_t)(k0 + br) * 64 + bc4);
    __syncthreads();
#pragma unroll
    for (int kk = 0; kk < OBK; ++kk) {
      float4 a = *(const float4*)&As[kk][ty * 4];
      float4 b0 = *(const float4*)&Bs[kk][tx * 8];
      float4 b1 = *(const float4*)&Bs[kk][tx * 8 + 4];
      float av[4] = {a.x, a.y, a.z, a.w};
      float bv[8] = {b0.x, b0.y, b0.z, b0.w, b1.x, b1.y, b1.z, b1.w};
#pragma unroll
      for (int i = 0; i < 4; ++i)
#pragma unroll
        for (int j = 0; j < 8; ++j) acc[i][j] = fmaf(av[i], bv[j], acc[i][j]);
    }
    __syncthreads();
  }

#pragma unroll
  for (int i = 0; i < 4; ++i) {
    int r = ty * 4 + i;
    *(float4*)&Ls[r][tx * 8] = make_float4(acc[i][0], acc[i][1], acc[i][2], acc[i][3]);
    *(float4*)&Ls[r][tx * 8 + 4] = make_float4(acc[i][4], acc[i][5], acc[i][6], acc[i][7]);
  }
  __syncthreads();

  int lane = tid & 63;
  int w = tid >> 6;
  for (int r = w * 32; r < w * 32 + 32; ++r) {
    int grow = m0 + r;
    if (grow >= M) break;
    float v = Ls[r][lane];
    float mx = v;
    for (int o = 32; o > 0; o >>= 1) mx = fmaxf(mx, __shfl_xor(mx, o, 64));
    float ex = expf(v - mx);
    float s = ex;
    for (int o = 32; o > 0; o >>= 1) s += __shfl_xor(s, o, 64);
    out[(size_t)grow * 64 + lane] = (v - mx) - logf(s);
  }
}

// ---------------- launch ----------------

extern "C" void kernel_launch(void* const* d_in, const int* in_sizes, int n_in,
                              void* d_out, int out_size, void* d_ws, size_t ws_size,
                              hipStream_t stream) {
  const float* x = (const float*)d_in[0];
  const int* ei = (const int*)d_in[1];
  const float* W1 = (const float*)d_in[2];
  const float* b1 = (const float*)d_in[3];
  const float* W2 = (const float*)d_in[4];
  const float* b2 = (const float*)d_in[5];
  const float* Wo = (const float*)d_in[6];
  const float* bo = (const float*)d_in[7];
  float* out = (float*)d_out;

  const int Dh = 256;
  const int N = in_sizes[0] / Dh;
  const int E = in_sizes[1] / 2;
  const int* srcv = ei;
  const int* dstv = ei + E;

  char* p = (char*)d_ws;
  auto take = [&](size_t bytes) {
    char* r = p;
    p += (bytes + 255) & ~(size_t)255;
    return r;
  };
  unsigned short* xbf = (unsigned short*)take((size_t)N * Dh * 2);
  unsigned short* hbuf1 = (unsigned short*)take((size_t)N * Dh * 2);
  unsigned short* hbuf2 = (unsigned short*)take((size_t)N * Dh * 2);
  unsigned short* Wt1 = (unsigned short*)take(256 * 256 * 2);
  unsigned short* Wt2 = (unsigned short*)take(256 * 256 * 2);
  float* dis = (float*)take((size_t)N * 4);
  int* cnt = (int*)take((size_t)N * 4);
  int* row_ptr = (int*)take((size_t)(N + 1) * 4);
  int* cursor = (int*)take((size_t)N * 4);
  int* col_src = (int*)take((size_t)E * 4);
  int* blk_sums = (int*)take(4096 * 4);

  int NB = (N + 1023) / 1024;

  // conversions + CSR (independent chains)
  long nx = (long)N * Dh;
  cvt_bf16_k<<<(int)((nx / 8 + TPB - 1) / TPB), TPB, 0, stream>>>(x, xbf, nx);
  wt_k<<<256, TPB, 0, stream>>>(W1, Wt1);
  wt_k<<<256, TPB, 0, stream>>>(W2, Wt2);
  zero_cnt_k<<<(N + TPB - 1) / TPB, TPB, 0, stream>>>(cnt, N);
  count_k<<<(E + TPB - 1) / TPB, TPB, 0, stream>>>(dstv, cnt, E);
  scan1_k<<<NB, TPB, 0, stream>>>(cnt, row_ptr, blk_sums, N);
  scan2_k<<<1, TPB, 0, stream>>>(blk_sums, NB);
  finalize_k<<<(N + TPB - 1) / TPB, TPB, 0, stream>>>(row_ptr, blk_sums, cursor, cnt, dis, N, E);
  fill_k<<<(E + TPB - 1) / TPB, TPB, 0, stream>>>(srcv, dstv, cursor, col_src, E);

  dim3 ggrid(2, (N + 127) / 128);

  // layer 1
  gemm_bf16_k<<<ggrid, TPB, 0, stream>>>(xbf, Wt1, hbuf1, N);
  aggregate_bf_k<<<(N + 3) / 4, TPB, 0, stream>>>(hbuf1, hbuf2, row_ptr, col_src, dis, b1, N);
  // layer 2
  gemm_bf16_k<<<ggrid, TPB, 0, stream>>>(hbuf2, Wt2, hbuf1, N);
  aggregate_bf_k<<<(N + 3) / 4, TPB, 0, stream>>>(hbuf1, hbuf2, row_ptr, col_src, dis, b2, N);
  // output layer + fused log_softmax
  outgemm_k<<<(N + OBM - 1) / OBM, TPB, 0, stream>>>(hbuf2, Wo, bo, out, N);
}

// Round 5
// 530.048 us; speedup vs baseline: 2.0302x; 1.1728x over previous
//
#include <hip/hip_runtime.h>
#include <math.h>

#define TPB 256

typedef short bf16x8 __attribute__((ext_vector_type(8)));
typedef unsigned short u16x8 __attribute__((ext_vector_type(8)));
typedef float f32x4 __attribute__((ext_vector_type(4)));

__device__ __forceinline__ float bf2f(unsigned short u) {
  union { unsigned int i; float f; } c;
  c.i = ((unsigned int)u) << 16;
  return c.f;
}
__device__ __forceinline__ unsigned short f2bf(float f) {
  union { float f; unsigned int i; } c;
  c.f = f;
  unsigned int r = c.i + 0x7FFFu + ((c.i >> 16) & 1u);
  return (unsigned short)(r >> 16);
}

// ---------------- CSR build ----------------

__global__ __launch_bounds__(TPB) void zero_cnt_k(int* __restrict__ cnt, int N) {
  int i = blockIdx.x * TPB + threadIdx.x;
  if (i < N) cnt[i] = 0;
}

__global__ __launch_bounds__(TPB) void count_k(const int* __restrict__ dstv,
                                               int* __restrict__ cnt, int E) {
  int e = blockIdx.x * TPB + threadIdx.x;
  if (e < E) atomicAdd(&cnt[dstv[e]], 1);
}

__global__ __launch_bounds__(TPB) void scan1_k(const int* __restrict__ cnt,
                                               int* __restrict__ excl,
                                               int* __restrict__ blk_sums, int N) {
  __shared__ int sh[TPB];
  int b = blockIdx.x, tid = threadIdx.x;
  int base = b * 1024 + tid * 4;
  int v[4];
  int sum = 0;
#pragma unroll
  for (int j = 0; j < 4; ++j) {
    int i = base + j;
    v[j] = (i < N) ? cnt[i] : 0;
    sum += v[j];
  }
  sh[tid] = sum;
  __syncthreads();
  for (int off = 1; off < TPB; off <<= 1) {
    int t = (tid >= off) ? sh[tid - off] : 0;
    __syncthreads();
    sh[tid] += t;
    __syncthreads();
  }
  if (tid == TPB - 1) blk_sums[b] = sh[TPB - 1];
  int run = (tid > 0) ? sh[tid - 1] : 0;
#pragma unroll
  for (int j = 0; j < 4; ++j) {
    int i = base + j;
    if (i < N) excl[i] = run;
    run += v[j];
  }
}

__global__ __launch_bounds__(TPB) void scan2_k(int* __restrict__ blk_sums, int NB) {
  __shared__ int sh[TPB];
  int tid = threadIdx.x;
  sh[tid] = (tid < NB) ? blk_sums[tid] : 0;
  __syncthreads();
  for (int off = 1; off < TPB; off <<= 1) {
    int t = (tid >= off) ? sh[tid - off] : 0;
    __syncthreads();
    sh[tid] += t;
    __syncthreads();
  }
  int ex = (tid > 0) ? sh[tid - 1] : 0;
  if (tid < NB) blk_sums[tid] = ex;
}

__global__ __launch_bounds__(TPB) void finalize_k(int* __restrict__ row_ptr,
                                                  const int* __restrict__ blk_sums,
                                                  int* __restrict__ cursor,
                                                  const int* __restrict__ cnt,
                                                  float* __restrict__ dis, int N, int E) {
  int i = blockIdx.x * TPB + threadIdx.x;
  if (i < N) {
    int r = row_ptr[i] + blk_sums[i >> 10];
    row_ptr[i] = r;
    cursor[i] = r;
    dis[i] = rsqrtf((float)(cnt[i] + 1));
  }
  if (blockIdx.x == 0 && threadIdx.x == 0) row_ptr[N] = E;
}

__global__ __launch_bounds__(TPB) void fill_k(const int* __restrict__ srcv,
                                              const int* __restrict__ dstv,
                                              int* __restrict__ cursor,
                                              int* __restrict__ col_src, int E) {
  int e = blockIdx.x * TPB + threadIdx.x;
  if (e < E) {
    int d = dstv[e];
    int pos = atomicAdd(&cursor[d], 1);
    col_src[pos] = srcv[e];
  }
}

// ---------------- conversions ----------------

__global__ __launch_bounds__(TPB) void cvt_bf16_k(const float* __restrict__ in,
                                                  unsigned short* __restrict__ out,
                                                  long n) {
  long i = ((long)blockIdx.x * TPB + threadIdx.x) * 8;
  if (i >= n) return;
  float4 a = *(const float4*)(in + i);
  float4 b = *(const float4*)(in + i + 4);
  ushort4 o0, o1;
  o0.x = f2bf(a.x); o0.y = f2bf(a.y); o0.z = f2bf(a.z); o0.w = f2bf(a.w);
  o1.x = f2bf(b.x); o1.y = f2bf(b.y); o1.z = f2bf(b.z); o1.w = f2bf(b.w);
  *(ushort4*)(out + i) = o0;
  *(ushort4*)(out + i + 4) = o1;
}

// Wt[n][k] = bf16(W[k][n]) for 256x256 weights
__global__ __launch_bounds__(TPB) void wt_k(const float* __restrict__ W,
                                            unsigned short* __restrict__ Wt) {
  int idx = blockIdx.x * TPB + threadIdx.x;
  int n = idx >> 8, k = idx & 255;
  Wt[n * 256 + k] = f2bf(W[k * 256 + n]);
}

// Wot[n][k] = bf16(Wo[k][n]) for 256x64 weight (n<64, k<256)
__global__ __launch_bounds__(TPB) void wot_k(const float* __restrict__ Wo,
                                             unsigned short* __restrict__ Wot) {
  int idx = blockIdx.x * TPB + threadIdx.x;  // 16384 total
  int n = idx >> 8, k = idx & 255;
  Wot[n * 256 + k] = f2bf(Wo[k * 64 + n]);
}

// ---------------- bf16 MFMA GEMM: C[M,256] = dis[row] * (A[M,256] @ Bt^T) ----------------

__global__ __launch_bounds__(TPB) void gemm_bf16_k(const unsigned short* __restrict__ A,
                                                   const unsigned short* __restrict__ Bt,
                                                   unsigned short* __restrict__ C,
                                                   const float* __restrict__ dis,
                                                   int M) {
  __shared__ unsigned short As[128 * 32];
  __shared__ unsigned short Bs[128 * 32];
  const int tid = threadIdx.x;
  const int m0 = blockIdx.y * 128;
  const int n0 = blockIdx.x * 128;
  const int lane = tid & 63;
  const int wid = tid >> 6;
  const int wr = (wid >> 1) * 64;
  const int wc = (wid & 1) * 64;

  const int srow = tid >> 1;
  const int scb0 = (tid & 1) * 2;
  const int grow = min(m0 + srow, M - 1);
  const unsigned short* gA = A + (size_t)grow * 256 + scb0 * 8;
  const unsigned short* gB = Bt + (size_t)(n0 + srow) * 256 + scb0 * 8;
  const int swz = (srow >> 1) & 3;
  const int ls0 = srow * 64 + ((scb0 ^ swz) << 4);
  const int ls1 = srow * 64 + (((scb0 + 1) ^ swz) << 4);

  const int r15 = lane & 15;
  const int cq = lane >> 4;
  const int swzr = (r15 >> 1) & 3;
  const int coff = ((cq ^ swzr) << 4);

  f32x4 acc[4][4];
#pragma unroll
  for (int i = 0; i < 4; ++i)
#pragma unroll
    for (int j = 0; j < 4; ++j)
#pragma unroll
      for (int r = 0; r < 4; ++r) acc[i][j][r] = 0.f;

  u16x8 ra0 = *(const u16x8*)(gA);
  u16x8 ra1 = *(const u16x8*)(gA + 8);
  u16x8 rb0 = *(const u16x8*)(gB);
  u16x8 rb1 = *(const u16x8*)(gB + 8);

  for (int kt = 0; kt < 8; ++kt) {
    __syncthreads();
    *(u16x8*)((char*)As + ls0) = ra0;
    *(u16x8*)((char*)As + ls1) = ra1;
    *(u16x8*)((char*)Bs + ls0) = rb0;
    *(u16x8*)((char*)Bs + ls1) = rb1;
    __syncthreads();
    if (kt < 7) {
      ra0 = *(const u16x8*)(gA + (kt + 1) * 32);
      ra1 = *(const u16x8*)(gA + (kt + 1) * 32 + 8);
      rb0 = *(const u16x8*)(gB + (kt + 1) * 32);
      rb1 = *(const u16x8*)(gB + (kt + 1) * 32 + 8);
    }
    bf16x8 af[4], bfr[4];
#pragma unroll
    for (int i = 0; i < 4; ++i)
      af[i] = *(const bf16x8*)((char*)As + (wr + i * 16 + r15) * 64 + coff);
#pragma unroll
    for (int j = 0; j < 4; ++j)
      bfr[j] = *(const bf16x8*)((char*)Bs + (wc + j * 16 + r15) * 64 + coff);
#pragma unroll
    for (int i = 0; i < 4; ++i)
#pragma unroll
      for (int j = 0; j < 4; ++j)
        acc[i][j] = __builtin_amdgcn_mfma_f32_16x16x32_bf16(af[i], bfr[j], acc[i][j], 0, 0, 0);
  }

#pragma unroll
  for (int i = 0; i < 4; ++i) {
#pragma unroll
    for (int r = 0; r < 4; ++r) {
      int row = m0 + wr + i * 16 + (lane >> 4) * 4 + r;
      if (row < M) {
        float dv = dis[row];
#pragma unroll
        for (int j = 0; j < 4; ++j) {
          C[(size_t)row * 256 + n0 + wc + j * 16 + r15] = f2bf(dv * acc[i][j][r]);
        }
      }
    }
  }
}

// ---------------- aggregation (pre-scaled H'): one wave per node ----------------
// O[v] = relu( dis[v] * (sum_{e:dst=v} H'[src] + H'[v]) + b ),  H' = dis*H

__global__ __launch_bounds__(TPB) void aggregate_bf_k(const unsigned short* __restrict__ H,
                                                      unsigned short* __restrict__ O,
                                                      const int* __restrict__ row_ptr,
                                                      const int* __restrict__ col_src,
                                                      const float* __restrict__ dis,
                                                      const float* __restrict__ bias,
                                                      int N) {
  int wid = (blockIdx.x * TPB + threadIdx.x) >> 6;
  int lane = threadIdx.x & 63;
  if (wid >= N) return;
  int beg = row_ptr[wid], end = row_ptr[wid + 1];

  float p0 = 0.f, p1 = 0.f, p2 = 0.f, p3 = 0.f;   // set A
  float q0 = 0.f, q1 = 0.f, q2 = 0.f, q3 = 0.f;   // set B
  float r0 = 0.f, r1 = 0.f, r2 = 0.f, r3 = 0.f;   // set C
  float t0 = 0.f, t1 = 0.f, t2 = 0.f, t3 = 0.f;   // set D

  int e = beg;
  for (; e + 4 <= end; e += 4) {
    int s0 = col_src[e + 0];
    int s1 = col_src[e + 1];
    int s2 = col_src[e + 2];
    int s3 = col_src[e + 3];
    ushort4 h0 = *(const ushort4*)(H + (size_t)s0 * 256 + lane * 4);
    ushort4 h1 = *(const ushort4*)(H + (size_t)s1 * 256 + lane * 4);
    ushort4 h2 = *(const ushort4*)(H + (size_t)s2 * 256 + lane * 4);
    ushort4 h3 = *(const ushort4*)(H + (size_t)s3 * 256 + lane * 4);
    p0 += bf2f(h0.x); p1 += bf2f(h0.y); p2 += bf2f(h0.z); p3 += bf2f(h0.w);
    q0 += bf2f(h1.x); q1 += bf2f(h1.y); q2 += bf2f(h1.z); q3 += bf2f(h1.w);
    r0 += bf2f(h2.x); r1 += bf2f(h2.y); r2 += bf2f(h2.z); r3 += bf2f(h2.w);
    t0 += bf2f(h3.x); t1 += bf2f(h3.y); t2 += bf2f(h3.z); t3 += bf2f(h3.w);
  }
  for (; e < end; ++e) {
    int s = col_src[e];
    ushort4 h = *(const ushort4*)(H + (size_t)s * 256 + lane * 4);
    p0 += bf2f(h.x); p1 += bf2f(h.y); p2 += bf2f(h.z); p3 += bf2f(h.w);
  }

  // self term
  ushort4 hv = *(const ushort4*)(H + (size_t)wid * 256 + lane * 4);
  p0 += bf2f(hv.x); p1 += bf2f(hv.y); p2 += bf2f(hv.z); p3 += bf2f(hv.w);

  float s0 = (p0 + q0) + (r0 + t0);
  float s1 = (p1 + q1) + (r1 + t1);
  float s2 = (p2 + q2) + (r2 + t2);
  float s3 = (p3 + q3) + (r3 + t3);

  float dv = dis[wid];
  float4 b = *(const float4*)(bias + lane * 4);
  ushort4 o;
  o.x = f2bf(fmaxf(fmaf(dv, s0, b.x), 0.f));
  o.y = f2bf(fmaxf(fmaf(dv, s1, b.y), 0.f));
  o.z = f2bf(fmaxf(fmaf(dv, s2, b.z), 0.f));
  o.w = f2bf(fmaxf(fmaf(dv, s3, b.w), 0.f));
  *(ushort4*)(O + (size_t)wid * 256 + lane * 4) = o;
}

// ---------------- MFMA output layer: logits = H @ Wot^T + bo ; log_softmax ----------------
// 128-row tile, 4 waves; wave w: rows w*32..w*32+31 (2 i-frags) x 64 cols (4 j-frags).

__global__ __launch_bounds__(TPB) void outgemm_k(const unsigned short* __restrict__ H,
                                                 const unsigned short* __restrict__ Wot,
                                                 const float* __restrict__ bo,
                                                 float* __restrict__ out, int M) {
  __shared__ unsigned short As[128 * 32];
  __shared__ unsigned short Bs[64 * 32];
  __shared__ float Ls[128][65];
  const int tid = threadIdx.x;
  const int m0 = blockIdx.x * 128;
  const int lane = tid & 63;
  const int w = tid >> 6;
  const int wr = w * 32;

  // A staging: row = tid>>1 (0..127), two 16B chunks
  const int srow = tid >> 1;
  const int scb0 = (tid & 1) * 2;
  const int grow = min(m0 + srow, M - 1);
  const unsigned short* gA = H + (size_t)grow * 256 + scb0 * 8;
  const int swz = (srow >> 1) & 3;
  const int lsa0 = srow * 64 + ((scb0 ^ swz) << 4);
  const int lsa1 = srow * 64 + (((scb0 + 1) ^ swz) << 4);

  // B staging: row = tid>>2 (0..63), one 16B chunk = tid&3
  const int brow = tid >> 2;
  const int bcb = tid & 3;
  const unsigned short* gB = Wot + (size_t)brow * 256 + bcb * 8;
  const int bswz = (brow >> 1) & 3;
  const int lsb = brow * 64 + ((bcb ^ bswz) << 4);

  const int r15 = lane & 15;
  const int cq = lane >> 4;
  const int swzr = (r15 >> 1) & 3;
  const int coff = ((cq ^ swzr) << 4);

  f32x4 acc[2][4];
#pragma unroll
  for (int i = 0; i < 2; ++i)
#pragma unroll
    for (int j = 0; j < 4; ++j)
#pragma unroll
      for (int r = 0; r < 4; ++r) acc[i][j][r] = 0.f;

  u16x8 ra0 = *(const u16x8*)(gA);
  u16x8 ra1 = *(const u16x8*)(gA + 8);
  u16x8 rb = *(const u16x8*)(gB);

  for (int kt = 0; kt < 8; ++kt) {
    __syncthreads();
    *(u16x8*)((char*)As + lsa0) = ra0;
    *(u16x8*)((char*)As + lsa1) = ra1;
    *(u16x8*)((char*)Bs + lsb) = rb;
    __syncthreads();
    if (kt < 7) {
      ra0 = *(const u16x8*)(gA + (kt + 1) * 32);
      ra1 = *(const u16x8*)(gA + (kt + 1) * 32 + 8);
      rb = *(const u16x8*)(gB + (kt + 1) * 32);
    }
    bf16x8 af[2], bfr[4];
#pragma unroll
    for (int i = 0; i < 2; ++i)
      af[i] = *(const bf16x8*)((char*)As + (wr + i * 16 + r15) * 64 + coff);
#pragma unroll
    for (int j = 0; j < 4; ++j)
      bfr[j] = *(const bf16x8*)((char*)Bs + (j * 16 + r15) * 64 + coff);
#pragma unroll
    for (int i = 0; i < 2; ++i)
#pragma unroll
      for (int j = 0; j < 4; ++j)
        acc[i][j] = __builtin_amdgcn_mfma_f32_16x16x32_bf16(af[i], bfr[j], acc[i][j], 0, 0, 0);
  }

  // logits (+bias) -> LDS
#pragma unroll
  for (int j = 0; j < 4; ++j) {
    float bj = bo[j * 16 + r15];
#pragma unroll
    for (int i = 0; i < 2; ++i)
#pragma unroll
      for (int r = 0; r < 4; ++r) {
        int rl = wr + i * 16 + (lane >> 4) * 4 + r;
        Ls[rl][j * 16 + r15] = acc[i][j][r] + bj;
      }
  }
  __syncthreads();

  // wave-per-row log_softmax
  for (int r = wr; r < wr + 32; ++r) {
    int gr = m0 + r;
    if (gr >= M) break;
    float v = Ls[r][lane];
    float mx = v;
    for (int o = 32; o > 0; o >>= 1) mx = fmaxf(mx, __shfl_xor(mx, o, 64));
    float ex = expf(v - mx);
    float s = ex;
    for (int o = 32; o > 0; o >>= 1) s += __shfl_xor(s, o, 64);
    out[(size_t)gr * 64 + lane] = (v - mx) - logf(s);
  }
}

// ---------------- launch ----------------

extern "C" void kernel_launch(void* const* d_in, const int* in_sizes, int n_in,
                              void* d_out, int out_size, void* d_ws, size_t ws_size,
                              hipStream_t stream) {
  const float* x = (const float*)d_in[0];
  const int* ei = (const int*)d_in[1];
  const float* W1 = (const float*)d_in[2];
  const float* b1 = (const float*)d_in[3];
  const float* W2 = (const float*)d_in[4];
  const float* b2 = (const float*)d_in[5];
  const float* Wo = (const float*)d_in[6];
  const float* bo = (const float*)d_in[7];
  float* out = (float*)d_out;

  const int Dh = 256;
  const int N = in_sizes[0] / Dh;
  const int E = in_sizes[1] / 2;
  const int* srcv = ei;
  const int* dstv = ei + E;

  char* p = (char*)d_ws;
  auto take = [&](size_t bytes) {
    char* r = p;
    p += (bytes + 255) & ~(size_t)255;
    return r;
  };
  unsigned short* xbf = (unsigned short*)take((size_t)N * Dh * 2);
  unsigned short* hbuf1 = (unsigned short*)take((size_t)N * Dh * 2);
  unsigned short* hbuf2 = (unsigned short*)take((size_t)N * Dh * 2);
  unsigned short* Wt1 = (unsigned short*)take(256 * 256 * 2);
  unsigned short* Wt2 = (unsigned short*)take(256 * 256 * 2);
  unsigned short* Wot = (unsigned short*)take(64 * 256 * 2);
  float* dis = (float*)take((size_t)N * 4);
  int* cnt = (int*)take((size_t)N * 4);
  int* row_ptr = (int*)take((size_t)(N + 1) * 4);
  int* cursor = (int*)take((size_t)N * 4);
  int* col_src = (int*)take((size_t)E * 4);
  int* blk_sums = (int*)take(4096 * 4);

  int NB = (N + 1023) / 1024;

  long nx = (long)N * Dh;
  cvt_bf16_k<<<(int)((nx / 8 + TPB - 1) / TPB), TPB, 0, stream>>>(x, xbf, nx);
  wt_k<<<256, TPB, 0, stream>>>(W1, Wt1);
  wt_k<<<256, TPB, 0, stream>>>(W2, Wt2);
  wot_k<<<64, TPB, 0, stream>>>(Wo, Wot);
  zero_cnt_k<<<(N + TPB - 1) / TPB, TPB, 0, stream>>>(cnt, N);
  count_k<<<(E + TPB - 1) / TPB, TPB, 0, stream>>>(dstv, cnt, E);
  scan1_k<<<NB, TPB, 0, stream>>>(cnt, row_ptr, blk_sums, N);
  scan2_k<<<1, TPB, 0, stream>>>(blk_sums, NB);
  finalize_k<<<(N + TPB - 1) / TPB, TPB, 0, stream>>>(row_ptr, blk_sums, cursor, cnt, dis, N, E);
  fill_k<<<(E + TPB - 1) / TPB, TPB, 0, stream>>>(srcv, dstv, cursor, col_src, E);

  dim3 ggrid(2, (N + 127) / 128);

  // layer 1 (gemm outputs dis-scaled H')
  gemm_bf16_k<<<ggrid, TPB, 0, stream>>>(xbf, Wt1, hbuf1, dis, N);
  aggregate_bf_k<<<(N + 3) / 4, TPB, 0, stream>>>(hbuf1, hbuf2, row_ptr, col_src, dis, b1, N);
  // layer 2
  gemm_bf16_k<<<ggrid, TPB, 0, stream>>>(hbuf2, Wt2, hbuf1, dis, N);
  aggregate_bf_k<<<(N + 3) / 4, TPB, 0, stream>>>(hbuf1, hbuf2, row_ptr, col_src, dis, b2, N);
  // output layer + fused log_softmax
  outgemm_k<<<(N + 127) / 128, TPB, 0, stream>>>(hbuf2, Wot, bo, out, N);
}

// Round 6
// 520.134 us; speedup vs baseline: 2.0689x; 1.0191x over previous
//
#include <hip/hip_runtime.h>
#include <math.h>

#define TPB 256

typedef short bf16x8 __attribute__((ext_vector_type(8)));
typedef unsigned short u16x8 __attribute__((ext_vector_type(8)));
typedef float f32x4 __attribute__((ext_vector_type(4)));

__device__ __forceinline__ float bf2f(unsigned short u) {
  union { unsigned int i; float f; } c;
  c.i = ((unsigned int)u) << 16;
  return c.f;
}
__device__ __forceinline__ unsigned short f2bf(float f) {
  union { float f; unsigned int i; } c;
  c.f = f;
  unsigned int r = c.i + 0x7FFFu + ((c.i >> 16) & 1u);
  return (unsigned short)(r >> 16);
}
__device__ __forceinline__ u16x8 pack8(float4 a, float4 b) {
  u16x8 r;
  r[0] = f2bf(a.x); r[1] = f2bf(a.y); r[2] = f2bf(a.z); r[3] = f2bf(a.w);
  r[4] = f2bf(b.x); r[5] = f2bf(b.y); r[6] = f2bf(b.z); r[7] = f2bf(b.w);
  return r;
}

// ---------------- CSR build ----------------

__global__ __launch_bounds__(TPB) void zero_cnt_k(int* __restrict__ cnt, int N) {
  int i = blockIdx.x * TPB + threadIdx.x;
  if (i < N) cnt[i] = 0;
}

__global__ __launch_bounds__(TPB) void count_k(const int* __restrict__ dstv,
                                               int* __restrict__ cnt, int E) {
  int e = blockIdx.x * TPB + threadIdx.x;
  if (e < E) atomicAdd(&cnt[dstv[e]], 1);
}

__global__ __launch_bounds__(TPB) void scan1_k(const int* __restrict__ cnt,
                                               int* __restrict__ excl,
                                               int* __restrict__ blk_sums, int N) {
  __shared__ int sh[TPB];
  int b = blockIdx.x, tid = threadIdx.x;
  int base = b * 1024 + tid * 4;
  int v[4];
  int sum = 0;
#pragma unroll
  for (int j = 0; j < 4; ++j) {
    int i = base + j;
    v[j] = (i < N) ? cnt[i] : 0;
    sum += v[j];
  }
  sh[tid] = sum;
  __syncthreads();
  for (int off = 1; off < TPB; off <<= 1) {
    int t = (tid >= off) ? sh[tid - off] : 0;
    __syncthreads();
    sh[tid] += t;
    __syncthreads();
  }
  if (tid == TPB - 1) blk_sums[b] = sh[TPB - 1];
  int run = (tid > 0) ? sh[tid - 1] : 0;
#pragma unroll
  for (int j = 0; j < 4; ++j) {
    int i = base + j;
    if (i < N) excl[i] = run;
    run += v[j];
  }
}

__global__ __launch_bounds__(TPB) void scan2_k(int* __restrict__ blk_sums, int NB) {
  __shared__ int sh[TPB];
  int tid = threadIdx.x;
  sh[tid] = (tid < NB) ? blk_sums[tid] : 0;
  __syncthreads();
  for (int off = 1; off < TPB; off <<= 1) {
    int t = (tid >= off) ? sh[tid - off] : 0;
    __syncthreads();
    sh[tid] += t;
    __syncthreads();
  }
  int ex = (tid > 0) ? sh[tid - 1] : 0;
  if (tid < NB) blk_sums[tid] = ex;
}

__global__ __launch_bounds__(TPB) void finalize_k(int* __restrict__ row_ptr,
                                                  const int* __restrict__ blk_sums,
                                                  int* __restrict__ cursor,
                                                  const int* __restrict__ cnt,
                                                  float* __restrict__ dis, int N, int E) {
  int i = blockIdx.x * TPB + threadIdx.x;
  if (i < N) {
    int r = row_ptr[i] + blk_sums[i >> 10];
    row_ptr[i] = r;
    cursor[i] = r;
    dis[i] = rsqrtf((float)(cnt[i] + 1));
  }
  if (blockIdx.x == 0 && threadIdx.x == 0) row_ptr[N] = E;
}

__global__ __launch_bounds__(TPB) void fill_k(const int* __restrict__ srcv,
                                              const int* __restrict__ dstv,
                                              int* __restrict__ cursor,
                                              int* __restrict__ col_src, int E) {
  int e = blockIdx.x * TPB + threadIdx.x;
  if (e < E) {
    int d = dstv[e];
    int pos = atomicAdd(&cursor[d], 1);
    col_src[pos] = srcv[e];
  }
}

// ---------------- weight transposes ----------------

// Wt[n][k] = bf16(W[k][n]) for 256x256 weights
__global__ __launch_bounds__(TPB) void wt_k(const float* __restrict__ W,
                                            unsigned short* __restrict__ Wt) {
  int idx = blockIdx.x * TPB + threadIdx.x;
  int n = idx >> 8, k = idx & 255;
  Wt[n * 256 + k] = f2bf(W[k * 256 + n]);
}

// Wot[n][k] = bf16(Wo[k][n]) for 256x64 weight (n<64, k<256)
__global__ __launch_bounds__(TPB) void wot_k(const float* __restrict__ Wo,
                                             unsigned short* __restrict__ Wot) {
  int idx = blockIdx.x * TPB + threadIdx.x;  // 16384 total
  int n = idx >> 8, k = idx & 255;
  Wot[n * 256 + k] = f2bf(Wo[k * 64 + n]);
}

// ---------------- bf16 MFMA GEMM: C[M,256] = dis[row] * (A[M,256] @ Bt^T) ----------------
// AF32: A is f32 (converted to bf16 in-register during staging); else A is bf16.

template <bool AF32>
__global__ __launch_bounds__(TPB) void gemm_bf16_t(const void* __restrict__ Araw,
                                                   const unsigned short* __restrict__ Bt,
                                                   unsigned short* __restrict__ C,
                                                   const float* __restrict__ dis,
                                                   int M) {
  __shared__ unsigned short As[128 * 32];
  __shared__ unsigned short Bs[128 * 32];
  const int tid = threadIdx.x;
  const int m0 = blockIdx.y * 128;
  const int n0 = blockIdx.x * 128;
  const int lane = tid & 63;
  const int wid = tid >> 6;
  const int wr = (wid >> 1) * 64;
  const int wc = (wid & 1) * 64;

  const int srow = tid >> 1;
  const int scb0 = (tid & 1) * 2;
  const int grow = min(m0 + srow, M - 1);
  const float* gA32 = (const float*)Araw + (size_t)grow * 256 + scb0 * 8;
  const unsigned short* gA16 = (const unsigned short*)Araw + (size_t)grow * 256 + scb0 * 8;
  const unsigned short* gB = Bt + (size_t)(n0 + srow) * 256 + scb0 * 8;
  const int swz = (srow >> 1) & 3;
  const int ls0 = srow * 64 + ((scb0 ^ swz) << 4);
  const int ls1 = srow * 64 + (((scb0 + 1) ^ swz) << 4);

  const int r15 = lane & 15;
  const int cq = lane >> 4;
  const int swzr = (r15 >> 1) & 3;
  const int coff = ((cq ^ swzr) << 4);

  f32x4 acc[4][4];
#pragma unroll
  for (int i = 0; i < 4; ++i)
#pragma unroll
    for (int j = 0; j < 4; ++j)
#pragma unroll
      for (int r = 0; r < 4; ++r) acc[i][j][r] = 0.f;

  u16x8 ra0, ra1;
  if constexpr (AF32) {
    float4 f0 = *(const float4*)(gA32);
    float4 f1 = *(const float4*)(gA32 + 4);
    float4 f2 = *(const float4*)(gA32 + 8);
    float4 f3 = *(const float4*)(gA32 + 12);
    ra0 = pack8(f0, f1);
    ra1 = pack8(f2, f3);
  } else {
    ra0 = *(const u16x8*)(gA16);
    ra1 = *(const u16x8*)(gA16 + 8);
  }
  u16x8 rb0 = *(const u16x8*)(gB);
  u16x8 rb1 = *(const u16x8*)(gB + 8);

  for (int kt = 0; kt < 8; ++kt) {
    __syncthreads();
    *(u16x8*)((char*)As + ls0) = ra0;
    *(u16x8*)((char*)As + ls1) = ra1;
    *(u16x8*)((char*)Bs + ls0) = rb0;
    *(u16x8*)((char*)Bs + ls1) = rb1;
    __syncthreads();
    if (kt < 7) {
      if constexpr (AF32) {
        float4 f0 = *(const float4*)(gA32 + (kt + 1) * 32);
        float4 f1 = *(const float4*)(gA32 + (kt + 1) * 32 + 4);
        float4 f2 = *(const float4*)(gA32 + (kt + 1) * 32 + 8);
        float4 f3 = *(const float4*)(gA32 + (kt + 1) * 32 + 12);
        ra0 = pack8(f0, f1);
        ra1 = pack8(f2, f3);
      } else {
        ra0 = *(const u16x8*)(gA16 + (kt + 1) * 32);
        ra1 = *(const u16x8*)(gA16 + (kt + 1) * 32 + 8);
      }
      rb0 = *(const u16x8*)(gB + (kt + 1) * 32);
      rb1 = *(const u16x8*)(gB + (kt + 1) * 32 + 8);
    }
    bf16x8 af[4], bfr[4];
#pragma unroll
    for (int i = 0; i < 4; ++i)
      af[i] = *(const bf16x8*)((char*)As + (wr + i * 16 + r15) * 64 + coff);
#pragma unroll
    for (int j = 0; j < 4; ++j)
      bfr[j] = *(const bf16x8*)((char*)Bs + (wc + j * 16 + r15) * 64 + coff);
#pragma unroll
    for (int i = 0; i < 4; ++i)
#pragma unroll
      for (int j = 0; j < 4; ++j)
        acc[i][j] = __builtin_amdgcn_mfma_f32_16x16x32_bf16(af[i], bfr[j], acc[i][j], 0, 0, 0);
  }

#pragma unroll
  for (int i = 0; i < 4; ++i) {
#pragma unroll
    for (int r = 0; r < 4; ++r) {
      int row = m0 + wr + i * 16 + (lane >> 4) * 4 + r;
      if (row < M) {
        float dv = dis[row];
#pragma unroll
        for (int j = 0; j < 4; ++j) {
          C[(size_t)row * 256 + n0 + wc + j * 16 + r15] = f2bf(dv * acc[i][j][r]);
        }
      }
    }
  }
}

// ---------------- aggregation (pre-scaled H'): one wave per node ----------------
// O[v] = relu( dis[v] * (sum_{e:dst=v} H'[src] + H'[v]) + b ),  H' = dis*H
// Half-wave (32 lanes x 16B) covers one row; one dwordx4 load fetches 2 edges.

__global__ __launch_bounds__(TPB) void aggregate_bf_k(const unsigned short* __restrict__ H,
                                                      unsigned short* __restrict__ O,
                                                      const int* __restrict__ row_ptr,
                                                      const int* __restrict__ col_src,
                                                      const float* __restrict__ dis,
                                                      const float* __restrict__ bias,
                                                      int N) {
  int wid = (blockIdx.x * TPB + threadIdx.x) >> 6;
  int lane = threadIdx.x & 63;
  if (wid >= N) return;
  const int half = lane >> 5;
  const int l5 = lane & 31;
  const size_t co = (size_t)l5 * 8;
  int beg = row_ptr[wid], end = row_ptr[wid + 1];

  float a0[8], a1[8], a2[8], a3[8];
#pragma unroll
  for (int j = 0; j < 8; ++j) { a0[j] = 0.f; a1[j] = 0.f; a2[j] = 0.f; a3[j] = 0.f; }

  int e = beg;
  for (; e + 8 <= end; e += 8) {
    int s0 = col_src[e + 0 + half];
    int s1 = col_src[e + 2 + half];
    int s2 = col_src[e + 4 + half];
    int s3 = col_src[e + 6 + half];
    u16x8 h0 = *(const u16x8*)(H + (size_t)s0 * 256 + co);
    u16x8 h1 = *(const u16x8*)(H + (size_t)s1 * 256 + co);
    u16x8 h2 = *(const u16x8*)(H + (size_t)s2 * 256 + co);
    u16x8 h3 = *(const u16x8*)(H + (size_t)s3 * 256 + co);
#pragma unroll
    for (int j = 0; j < 8; ++j) {
      a0[j] += bf2f(h0[j]);
      a1[j] += bf2f(h1[j]);
      a2[j] += bf2f(h2[j]);
      a3[j] += bf2f(h3[j]);
    }
  }
  for (; e < end; e += 2) {
    int idx = e + half;
    int ok = idx < end;
    int s = ok ? col_src[idx] : wid;  // self row: safe dummy
    u16x8 h = *(const u16x8*)(H + (size_t)s * 256 + co);
    float m = ok ? 1.f : 0.f;
#pragma unroll
    for (int j = 0; j < 8; ++j) a0[j] = fmaf(m, bf2f(h[j]), a0[j]);
  }

  float s[8];
#pragma unroll
  for (int j = 0; j < 8; ++j) s[j] = (a0[j] + a1[j]) + (a2[j] + a3[j]);
  // merge the two half-wave edge sets
#pragma unroll
  for (int j = 0; j < 8; ++j) s[j] += __shfl_xor(s[j], 32, 64);

  // self term
  u16x8 hv = *(const u16x8*)(H + (size_t)wid * 256 + co);
#pragma unroll
  for (int j = 0; j < 8; ++j) s[j] += bf2f(hv[j]);

  float dv = dis[wid];
  float4 b0 = *(const float4*)(bias + l5 * 8);
  float4 b1 = *(const float4*)(bias + l5 * 8 + 4);
  float bb[8] = {b0.x, b0.y, b0.z, b0.w, b1.x, b1.y, b1.z, b1.w};
  u16x8 o;
#pragma unroll
  for (int j = 0; j < 8; ++j) o[j] = f2bf(fmaxf(fmaf(dv, s[j], bb[j]), 0.f));
  if (half == 0) *(u16x8*)(O + (size_t)wid * 256 + co) = o;
}

// ---------------- MFMA output layer: logits = H @ Wot^T + bo ; log_softmax ----------------

__global__ __launch_bounds__(TPB) void outgemm_k(const unsigned short* __restrict__ H,
                                                 const unsigned short* __restrict__ Wot,
                                                 const float* __restrict__ bo,
                                                 float* __restrict__ out, int M) {
  __shared__ unsigned short As[128 * 32];
  __shared__ unsigned short Bs[64 * 32];
  __shared__ float Ls[128][65];
  const int tid = threadIdx.x;
  const int m0 = blockIdx.x * 128;
  const int lane = tid & 63;
  const int w = tid >> 6;
  const int wr = w * 32;

  const int srow = tid >> 1;
  const int scb0 = (tid & 1) * 2;
  const int grow = min(m0 + srow, M - 1);
  const unsigned short* gA = H + (size_t)grow * 256 + scb0 * 8;
  const int swz = (srow >> 1) & 3;
  const int lsa0 = srow * 64 + ((scb0 ^ swz) << 4);
  const int lsa1 = srow * 64 + (((scb0 + 1) ^ swz) << 4);

  const int brow = tid >> 2;
  const int bcb = tid & 3;
  const unsigned short* gB = Wot + (size_t)brow * 256 + bcb * 8;
  const int bswz = (brow >> 1) & 3;
  const int lsb = brow * 64 + ((bcb ^ bswz) << 4);

  const int r15 = lane & 15;
  const int cq = lane >> 4;
  const int swzr = (r15 >> 1) & 3;
  const int coff = ((cq ^ swzr) << 4);

  f32x4 acc[2][4];
#pragma unroll
  for (int i = 0; i < 2; ++i)
#pragma unroll
    for (int j = 0; j < 4; ++j)
#pragma unroll
      for (int r = 0; r < 4; ++r) acc[i][j][r] = 0.f;

  u16x8 ra0 = *(const u16x8*)(gA);
  u16x8 ra1 = *(const u16x8*)(gA + 8);
  u16x8 rb = *(const u16x8*)(gB);

  for (int kt = 0; kt < 8; ++kt) {
    __syncthreads();
    *(u16x8*)((char*)As + lsa0) = ra0;
    *(u16x8*)((char*)As + lsa1) = ra1;
    *(u16x8*)((char*)Bs + lsb) = rb;
    __syncthreads();
    if (kt < 7) {
      ra0 = *(const u16x8*)(gA + (kt + 1) * 32);
      ra1 = *(const u16x8*)(gA + (kt + 1) * 32 + 8);
      rb = *(const u16x8*)(gB + (kt + 1) * 32);
    }
    bf16x8 af[2], bfr[4];
#pragma unroll
    for (int i = 0; i < 2; ++i)
      af[i] = *(const bf16x8*)((char*)As + (wr + i * 16 + r15) * 64 + coff);
#pragma unroll
    for (int j = 0; j < 4; ++j)
      bfr[j] = *(const bf16x8*)((char*)Bs + (j * 16 + r15) * 64 + coff);
#pragma unroll
    for (int i = 0; i < 2; ++i)
#pragma unroll
      for (int j = 0; j < 4; ++j)
        acc[i][j] = __builtin_amdgcn_mfma_f32_16x16x32_bf16(af[i], bfr[j], acc[i][j], 0, 0, 0);
  }

#pragma unroll
  for (int j = 0; j < 4; ++j) {
    float bj = bo[j * 16 + r15];
#pragma unroll
    for (int i = 0; i < 2; ++i)
#pragma unroll
      for (int r = 0; r < 4; ++r) {
        int rl = wr + i * 16 + (lane >> 4) * 4 + r;
        Ls[rl][j * 16 + r15] = acc[i][j][r] + bj;
      }
  }
  __syncthreads();

  for (int r = wr; r < wr + 32; ++r) {
    int gr = m0 + r;
    if (gr >= M) break;
    float v = Ls[r][lane];
    float mx = v;
    for (int o = 32; o > 0; o >>= 1) mx = fmaxf(mx, __shfl_xor(mx, o, 64));
    float ex = expf(v - mx);
    float sm = ex;
    for (int o = 32; o > 0; o >>= 1) sm += __shfl_xor(sm, o, 64);
    out[(size_t)gr * 64 + lane] = (v - mx) - logf(sm);
  }
}

// ---------------- launch ----------------

extern "C" void kernel_launch(void* const* d_in, const int* in_sizes, int n_in,
                              void* d_out, int out_size, void* d_ws, size_t ws_size,
                              hipStream_t stream) {
  const float* x = (const float*)d_in[0];
  const int* ei = (const int*)d_in[1];
  const float* W1 = (const float*)d_in[2];
  const float* b1 = (const float*)d_in[3];
  const float* W2 = (const float*)d_in[4];
  const float* b2 = (const float*)d_in[5];
  const float* Wo = (const float*)d_in[6];
  const float* bo = (const float*)d_in[7];
  float* out = (float*)d_out;

  const int Dh = 256;
  const int N = in_sizes[0] / Dh;
  const int E = in_sizes[1] / 2;
  const int* srcv = ei;
  const int* dstv = ei + E;

  char* p = (char*)d_ws;
  auto take = [&](size_t bytes) {
    char* r = p;
    p += (bytes + 255) & ~(size_t)255;
    return r;
  };
  unsigned short* hbuf1 = (unsigned short*)take((size_t)N * Dh * 2);
  unsigned short* hbuf2 = (unsigned short*)take((size_t)N * Dh * 2);
  unsigned short* Wt1 = (unsigned short*)take(256 * 256 * 2);
  unsigned short* Wt2 = (unsigned short*)take(256 * 256 * 2);
  unsigned short* Wot = (unsigned short*)take(64 * 256 * 2);
  float* dis = (float*)take((size_t)N * 4);
  int* cnt = (int*)take((size_t)N * 4);
  int* row_ptr = (int*)take((size_t)(N + 1) * 4);
  int* cursor = (int*)take((size_t)N * 4);
  int* col_src = (int*)take((size_t)E * 4);
  int* blk_sums = (int*)take(4096 * 4);

  int NB = (N + 1023) / 1024;

  wt_k<<<256, TPB, 0, stream>>>(W1, Wt1);
  wt_k<<<256, TPB, 0, stream>>>(W2, Wt2);
  wot_k<<<64, TPB, 0, stream>>>(Wo, Wot);
  zero_cnt_k<<<(N + TPB - 1) / TPB, TPB, 0, stream>>>(cnt, N);
  count_k<<<(E + TPB - 1) / TPB, TPB, 0, stream>>>(dstv, cnt, E);
  scan1_k<<<NB, TPB, 0, stream>>>(cnt, row_ptr, blk_sums, N);
  scan2_k<<<1, TPB, 0, stream>>>(blk_sums, NB);
  finalize_k<<<(N + TPB - 1) / TPB, TPB, 0, stream>>>(row_ptr, blk_sums, cursor, cnt, dis, N, E);
  fill_k<<<(E + TPB - 1) / TPB, TPB, 0, stream>>>(srcv, dstv, cursor, col_src, E);

  dim3 ggrid(2, (N + 127) / 128);

  // layer 1 (gemm reads f32 x directly, outputs dis-scaled H')
  gemm_bf16_t<true><<<ggrid, TPB, 0, stream>>>((const void*)x, Wt1, hbuf1, dis, N);
  aggregate_bf_k<<<(N + 3) / 4, TPB, 0, stream>>>(hbuf1, hbuf2, row_ptr, col_src, dis, b1, N);
  // layer 2
  gemm_bf16_t<false><<<ggrid, TPB, 0, stream>>>((const void*)hbuf2, Wt2, hbuf1, dis, N);
  aggregate_bf_k<<<(N + 3) / 4, TPB, 0, stream>>>(hbuf1, hbuf2, row_ptr, col_src, dis, b2, N);
  // output layer + fused log_softmax
  outgemm_k<<<(N + 127) / 128, TPB, 0, stream>>>(hbuf2, Wot, bo, out, N);
}

// Round 8
// 508.214 us; speedup vs baseline: 2.1175x; 1.0235x over previous
//
#include <hip/hip_runtime.h>
#include <math.h>

#define TPB 256

typedef short bf16x8 __attribute__((ext_vector_type(8)));
typedef unsigned short u16x8 __attribute__((ext_vector_type(8)));
typedef float f32x4 __attribute__((ext_vector_type(4)));

__device__ __forceinline__ float bf2f(unsigned short u) {
  union { unsigned int i; float f; } c;
  c.i = ((unsigned int)u) << 16;
  return c.f;
}
__device__ __forceinline__ unsigned short f2bf(float f) {
  union { float f; unsigned int i; } c;
  c.f = f;
  unsigned int r = c.i + 0x7FFFu + ((c.i >> 16) & 1u);
  return (unsigned short)(r >> 16);
}
__device__ __forceinline__ u16x8 pack8(float4 a, float4 b) {
  u16x8 r;
  r[0] = f2bf(a.x); r[1] = f2bf(a.y); r[2] = f2bf(a.z); r[3] = f2bf(a.w);
  r[4] = f2bf(b.x); r[5] = f2bf(b.y); r[6] = f2bf(b.z); r[7] = f2bf(b.w);
  return r;
}

// ---------------- CSR build ----------------

__global__ __launch_bounds__(TPB) void zero_cnt_k(int* __restrict__ cnt, int N) {
  int i = blockIdx.x * TPB + threadIdx.x;
  if (i < N) cnt[i] = 0;
}

__global__ __launch_bounds__(TPB) void count_k(const int* __restrict__ dstv,
                                               int* __restrict__ cnt, int E) {
  int e = blockIdx.x * TPB + threadIdx.x;
  if (e < E) atomicAdd(&cnt[dstv[e]], 1);
}

__global__ __launch_bounds__(TPB) void scan1_k(const int* __restrict__ cnt,
                                               int* __restrict__ excl,
                                               int* __restrict__ blk_sums, int N) {
  __shared__ int sh[TPB];
  int b = blockIdx.x, tid = threadIdx.x;
  int base = b * 1024 + tid * 4;
  int v[4];
  int sum = 0;
#pragma unroll
  for (int j = 0; j < 4; ++j) {
    int i = base + j;
    v[j] = (i < N) ? cnt[i] : 0;
    sum += v[j];
  }
  sh[tid] = sum;
  __syncthreads();
  for (int off = 1; off < TPB; off <<= 1) {
    int t = (tid >= off) ? sh[tid - off] : 0;
    __syncthreads();
    sh[tid] += t;
    __syncthreads();
  }
  if (tid == TPB - 1) blk_sums[b] = sh[TPB - 1];
  int run = (tid > 0) ? sh[tid - 1] : 0;
#pragma unroll
  for (int j = 0; j < 4; ++j) {
    int i = base + j;
    if (i < N) excl[i] = run;
    run += v[j];
  }
}

__global__ __launch_bounds__(TPB) void scan2_k(int* __restrict__ blk_sums, int NB) {
  __shared__ int sh[TPB];
  int tid = threadIdx.x;
  sh[tid] = (tid < NB) ? blk_sums[tid] : 0;
  __syncthreads();
  for (int off = 1; off < TPB; off <<= 1) {
    int t = (tid >= off) ? sh[tid - off] : 0;
    __syncthreads();
    sh[tid] += t;
    __syncthreads();
  }
  int ex = (tid > 0) ? sh[tid - 1] : 0;
  if (tid < NB) blk_sums[tid] = ex;
}

__global__ __launch_bounds__(TPB) void finalize_k(int* __restrict__ row_ptr,
                                                  const int* __restrict__ blk_sums,
                                                  int* __restrict__ cursor,
                                                  const int* __restrict__ cnt,
                                                  float* __restrict__ dis, int N, int E) {
  int i = blockIdx.x * TPB + threadIdx.x;
  if (i < N) {
    int r = row_ptr[i] + blk_sums[i >> 10];
    row_ptr[i] = r;
    cursor[i] = r;
    dis[i] = rsqrtf((float)(cnt[i] + 1));
  }
  if (blockIdx.x == 0 && threadIdx.x == 0) row_ptr[N] = E;
}

__global__ __launch_bounds__(TPB) void fill_k(const int* __restrict__ srcv,
                                              const int* __restrict__ dstv,
                                              int* __restrict__ cursor,
                                              int* __restrict__ col_src, int E) {
  int e = blockIdx.x * TPB + threadIdx.x;
  if (e < E) {
    int d = dstv[e];
    int pos = atomicAdd(&cursor[d], 1);
    col_src[pos] = srcv[e];
  }
}

// ---------------- weight transposes ----------------

__global__ __launch_bounds__(TPB) void wt_k(const float* __restrict__ W,
                                            unsigned short* __restrict__ Wt) {
  int idx = blockIdx.x * TPB + threadIdx.x;
  int n = idx >> 8, k = idx & 255;
  Wt[n * 256 + k] = f2bf(W[k * 256 + n]);
}

__global__ __launch_bounds__(TPB) void wot_k(const float* __restrict__ Wo,
                                             unsigned short* __restrict__ Wot) {
  int idx = blockIdx.x * TPB + threadIdx.x;  // 16384 total
  int n = idx >> 8, k = idx & 255;
  Wot[n * 256 + k] = f2bf(Wo[k * 64 + n]);
}

// ---------------- bf16 MFMA GEMM: C[M,256] = dis[row] * (A[M,256] @ Bt^T) ----------------
// Double-buffered LDS, one barrier per K-step. XCD-pairing swizzle: the two
// n-halves of a row-block land on the same XCD (bid and bid+8).

template <bool AF32>
__global__ __launch_bounds__(TPB) void gemm_bf16_t(const void* __restrict__ Araw,
                                                   const unsigned short* __restrict__ Bt,
                                                   unsigned short* __restrict__ C,
                                                   const float* __restrict__ dis,
                                                   int M, int nyb) {
  __shared__ unsigned short As[2][128 * 32];
  __shared__ unsigned short Bs[2][128 * 32];
  const int bid = blockIdx.x;
  const int xcd = bid & 7;
  const int s = bid >> 3;
  const int nsel = s & 1;
  const int yb = (s >> 1) * 8 + xcd;
  if (yb >= nyb) return;
  const int m0 = yb * 128;
  const int n0 = nsel * 128;

  const int tid = threadIdx.x;
  const int lane = tid & 63;
  const int wid = tid >> 6;
  const int wr = (wid >> 1) * 64;
  const int wc = (wid & 1) * 64;

  const int srow = tid >> 1;
  const int scb0 = (tid & 1) * 2;
  const int grow = min(m0 + srow, M - 1);
  const float* gA32 = (const float*)Araw + (size_t)grow * 256 + scb0 * 8;
  const unsigned short* gA16 = (const unsigned short*)Araw + (size_t)grow * 256 + scb0 * 8;
  const unsigned short* gB = Bt + (size_t)(n0 + srow) * 256 + scb0 * 8;
  const int swz = (srow >> 1) & 3;
  const int ls0 = srow * 64 + ((scb0 ^ swz) << 4);
  const int ls1 = srow * 64 + (((scb0 + 1) ^ swz) << 4);

  const int r15 = lane & 15;
  const int cq = lane >> 4;
  const int swzr = (r15 >> 1) & 3;
  const int coff = ((cq ^ swzr) << 4);

  f32x4 acc[4][4];
#pragma unroll
  for (int i = 0; i < 4; ++i)
#pragma unroll
    for (int j = 0; j < 4; ++j)
#pragma unroll
      for (int r = 0; r < 4; ++r) acc[i][j][r] = 0.f;

  u16x8 ra0, ra1;
  if constexpr (AF32) {
    float4 f0 = *(const float4*)(gA32);
    float4 f1 = *(const float4*)(gA32 + 4);
    float4 f2 = *(const float4*)(gA32 + 8);
    float4 f3 = *(const float4*)(gA32 + 12);
    ra0 = pack8(f0, f1);
    ra1 = pack8(f2, f3);
  } else {
    ra0 = *(const u16x8*)(gA16);
    ra1 = *(const u16x8*)(gA16 + 8);
  }
  u16x8 rb0 = *(const u16x8*)(gB);
  u16x8 rb1 = *(const u16x8*)(gB + 8);

  for (int kt = 0; kt < 8; ++kt) {
    const int cur = kt & 1;
    // write current tile into buffer `cur`
    *(u16x8*)((char*)As[cur] + ls0) = ra0;
    *(u16x8*)((char*)As[cur] + ls1) = ra1;
    *(u16x8*)((char*)Bs[cur] + ls0) = rb0;
    *(u16x8*)((char*)Bs[cur] + ls1) = rb1;
    __syncthreads();  // single barrier per K-step (dbuf covers the W/R hazard)
    if (kt < 7) {     // prefetch next tile; in flight during ds_read+MFMA
      if constexpr (AF32) {
        float4 f0 = *(const float4*)(gA32 + (kt + 1) * 32);
        float4 f1 = *(const float4*)(gA32 + (kt + 1) * 32 + 4);
        float4 f2 = *(const float4*)(gA32 + (kt + 1) * 32 + 8);
        float4 f3 = *(const float4*)(gA32 + (kt + 1) * 32 + 12);
        ra0 = pack8(f0, f1);
        ra1 = pack8(f2, f3);
      } else {
        ra0 = *(const u16x8*)(gA16 + (kt + 1) * 32);
        ra1 = *(const u16x8*)(gA16 + (kt + 1) * 32 + 8);
      }
      rb0 = *(const u16x8*)(gB + (kt + 1) * 32);
      rb1 = *(const u16x8*)(gB + (kt + 1) * 32 + 8);
    }
    bf16x8 af[4], bfr[4];
#pragma unroll
    for (int i = 0; i < 4; ++i)
      af[i] = *(const bf16x8*)((char*)As[cur] + (wr + i * 16 + r15) * 64 + coff);
#pragma unroll
    for (int j = 0; j < 4; ++j)
      bfr[j] = *(const bf16x8*)((char*)Bs[cur] + (wc + j * 16 + r15) * 64 + coff);
#pragma unroll
    for (int i = 0; i < 4; ++i)
#pragma unroll
      for (int j = 0; j < 4; ++j)
        acc[i][j] = __builtin_amdgcn_mfma_f32_16x16x32_bf16(af[i], bfr[j], acc[i][j], 0, 0, 0);
  }

#pragma unroll
  for (int i = 0; i < 4; ++i) {
#pragma unroll
    for (int r = 0; r < 4; ++r) {
      int row = m0 + wr + i * 16 + (lane >> 4) * 4 + r;
      if (row < M) {
        float dv = dis[row];
#pragma unroll
        for (int j = 0; j < 4; ++j) {
          C[(size_t)row * 256 + n0 + wc + j * 16 + r15] = f2bf(dv * acc[i][j][r]);
        }
      }
    }
  }
}

// ---------------- aggregation (pre-scaled H'): one wave per node ----------------
// O[v] = relu( dis[v] * (sum_{e:dst=v} H'[src] + H'[v]) + b ),  H' = dis*H
// Round-5 structure: 8B/lane, 4-edge unroll, 16 scalar accumulators (VGPR-lean).

__global__ __launch_bounds__(TPB) void aggregate_bf_k(const unsigned short* __restrict__ H,
                                                      unsigned short* __restrict__ O,
                                                      const int* __restrict__ row_ptr,
                                                      const int* __restrict__ col_src,
                                                      const float* __restrict__ dis,
                                                      const float* __restrict__ bias,
                                                      int N) {
  int wid = (blockIdx.x * TPB + threadIdx.x) >> 6;
  int lane = threadIdx.x & 63;
  if (wid >= N) return;
  int beg = row_ptr[wid], end = row_ptr[wid + 1];

  float p0 = 0.f, p1 = 0.f, p2 = 0.f, p3 = 0.f;
  float q0 = 0.f, q1 = 0.f, q2 = 0.f, q3 = 0.f;
  float r0 = 0.f, r1 = 0.f, r2 = 0.f, r3 = 0.f;
  float t0 = 0.f, t1 = 0.f, t2 = 0.f, t3 = 0.f;

  int e = beg;
  for (; e + 4 <= end; e += 4) {
    int s0 = col_src[e + 0];
    int s1 = col_src[e + 1];
    int s2 = col_src[e + 2];
    int s3 = col_src[e + 3];
    ushort4 h0 = *(const ushort4*)(H + (size_t)s0 * 256 + lane * 4);
    ushort4 h1 = *(const ushort4*)(H + (size_t)s1 * 256 + lane * 4);
    ushort4 h2 = *(const ushort4*)(H + (size_t)s2 * 256 + lane * 4);
    ushort4 h3 = *(const ushort4*)(H + (size_t)s3 * 256 + lane * 4);
    p0 += bf2f(h0.x); p1 += bf2f(h0.y); p2 += bf2f(h0.z); p3 += bf2f(h0.w);
    q0 += bf2f(h1.x); q1 += bf2f(h1.y); q2 += bf2f(h1.z); q3 += bf2f(h1.w);
    r0 += bf2f(h2.x); r1 += bf2f(h2.y); r2 += bf2f(h2.z); r3 += bf2f(h2.w);
    t0 += bf2f(h3.x); t1 += bf2f(h3.y); t2 += bf2f(h3.z); t3 += bf2f(h3.w);
  }
  for (; e < end; ++e) {
    int s = col_src[e];
    ushort4 h = *(const ushort4*)(H + (size_t)s * 256 + lane * 4);
    p0 += bf2f(h.x); p1 += bf2f(h.y); p2 += bf2f(h.z); p3 += bf2f(h.w);
  }

  // self term
  ushort4 hv = *(const ushort4*)(H + (size_t)wid * 256 + lane * 4);
  p0 += bf2f(hv.x); p1 += bf2f(hv.y); p2 += bf2f(hv.z); p3 += bf2f(hv.w);

  float s0 = (p0 + q0) + (r0 + t0);
  float s1 = (p1 + q1) + (r1 + t1);
  float s2 = (p2 + q2) + (r2 + t2);
  float s3 = (p3 + q3) + (r3 + t3);

  float dv = dis[wid];
  float4 b = *(const float4*)(bias + lane * 4);
  ushort4 o;
  o.x = f2bf(fmaxf(fmaf(dv, s0, b.x), 0.f));
  o.y = f2bf(fmaxf(fmaf(dv, s1, b.y), 0.f));
  o.z = f2bf(fmaxf(fmaf(dv, s2, b.z), 0.f));
  o.w = f2bf(fmaxf(fmaf(dv, s3, b.w), 0.f));
  *(ushort4*)(O + (size_t)wid * 256 + lane * 4) = o;
}

// ---------------- MFMA output layer: logits = H @ Wot^T + bo ; log_softmax ----------------

__global__ __launch_bounds__(TPB) void outgemm_k(const unsigned short* __restrict__ H,
                                                 const unsigned short* __restrict__ Wot,
                                                 const float* __restrict__ bo,
                                                 float* __restrict__ out, int M) {
  __shared__ unsigned short As[128 * 32];
  __shared__ unsigned short Bs[64 * 32];
  __shared__ float Ls[128][65];
  const int tid = threadIdx.x;
  const int m0 = blockIdx.x * 128;
  const int lane = tid & 63;
  const int w = tid >> 6;
  const int wr = w * 32;

  const int srow = tid >> 1;
  const int scb0 = (tid & 1) * 2;
  const int grow = min(m0 + srow, M - 1);
  const unsigned short* gA = H + (size_t)grow * 256 + scb0 * 8;
  const int swz = (srow >> 1) & 3;
  const int lsa0 = srow * 64 + ((scb0 ^ swz) << 4);
  const int lsa1 = srow * 64 + (((scb0 + 1) ^ swz) << 4);

  const int brow = tid >> 2;
  const int bcb = tid & 3;
  const unsigned short* gB = Wot + (size_t)brow * 256 + bcb * 8;
  const int bswz = (brow >> 1) & 3;
  const int lsb = brow * 64 + ((bcb ^ bswz) << 4);

  const int r15 = lane & 15;
  const int cq = lane >> 4;
  const int swzr = (r15 >> 1) & 3;
  const int coff = ((cq ^ swzr) << 4);

  f32x4 acc[2][4];
#pragma unroll
  for (int i = 0; i < 2; ++i)
#pragma unroll
    for (int j = 0; j < 4; ++j)
#pragma unroll
      for (int r = 0; r < 4; ++r) acc[i][j][r] = 0.f;

  u16x8 ra0 = *(const u16x8*)(gA);
  u16x8 ra1 = *(const u16x8*)(gA + 8);
  u16x8 rb = *(const u16x8*)(gB);

  for (int kt = 0; kt < 8; ++kt) {
    __syncthreads();
    *(u16x8*)((char*)As + lsa0) = ra0;
    *(u16x8*)((char*)As + lsa1) = ra1;
    *(u16x8*)((char*)Bs + lsb) = rb;
    __syncthreads();
    if (kt < 7) {
      ra0 = *(const u16x8*)(gA + (kt + 1) * 32);
      ra1 = *(const u16x8*)(gA + (kt + 1) * 32 + 8);
      rb = *(const u16x8*)(gB + (kt + 1) * 32);
    }
    bf16x8 af[2], bfr[4];
#pragma unroll
    for (int i = 0; i < 2; ++i)
      af[i] = *(const bf16x8*)((char*)As + (wr + i * 16 + r15) * 64 + coff);
#pragma unroll
    for (int j = 0; j < 4; ++j)
      bfr[j] = *(const bf16x8*)((char*)Bs + (j * 16 + r15) * 64 + coff);
#pragma unroll
    for (int i = 0; i < 2; ++i)
#pragma unroll
      for (int j = 0; j < 4; ++j)
        acc[i][j] = __builtin_amdgcn_mfma_f32_16x16x32_bf16(af[i], bfr[j], acc[i][j], 0, 0, 0);
  }

#pragma unroll
  for (int j = 0; j < 4; ++j) {
    float bj = bo[j * 16 + r15];
#pragma unroll
    for (int i = 0; i < 2; ++i)
#pragma unroll
      for (int r = 0; r < 4; ++r) {
        int rl = wr + i * 16 + (lane >> 4) * 4 + r;
        Ls[rl][j * 16 + r15] = acc[i][j][r] + bj;
      }
  }
  __syncthreads();

  for (int r = wr; r < wr + 32; ++r) {
    int gr = m0 + r;
    if (gr >= M) break;
    float v = Ls[r][lane];
    float mx = v;
    for (int o = 32; o > 0; o >>= 1) mx = fmaxf(mx, __shfl_xor(mx, o, 64));
    float ex = expf(v - mx);
    float sm = ex;
    for (int o = 32; o > 0; o >>= 1) sm += __shfl_xor(sm, o, 64);
    out[(size_t)gr * 64 + lane] = (v - mx) - logf(sm);
  }
}

// ---------------- launch ----------------

extern "C" void kernel_launch(void* const* d_in, const int* in_sizes, int n_in,
                              void* d_out, int out_size, void* d_ws, size_t ws_size,
                              hipStream_t stream) {
  const float* x = (const float*)d_in[0];
  const int* ei = (const int*)d_in[1];
  const float* W1 = (const float*)d_in[2];
  const float* b1 = (const float*)d_in[3];
  const float* W2 = (const float*)d_in[4];
  const float* b2 = (const float*)d_in[5];
  const float* Wo = (const float*)d_in[6];
  const float* bo = (const float*)d_in[7];
  float* out = (float*)d_out;

  const int Dh = 256;
  const int N = in_sizes[0] / Dh;
  const int E = in_sizes[1] / 2;
  const int* srcv = ei;
  const int* dstv = ei + E;

  char* p = (char*)d_ws;
  auto take = [&](size_t bytes) {
    char* r = p;
    p += (bytes + 255) & ~(size_t)255;
    return r;
  };
  unsigned short* hbuf1 = (unsigned short*)take((size_t)N * Dh * 2);
  unsigned short* hbuf2 = (unsigned short*)take((size_t)N * Dh * 2);
  unsigned short* Wt1 = (unsigned short*)take(256 * 256 * 2);
  unsigned short* Wt2 = (unsigned short*)take(256 * 256 * 2);
  unsigned short* Wot = (unsigned short*)take(64 * 256 * 2);
  float* dis = (float*)take((size_t)N * 4);
  int* cnt = (int*)take((size_t)N * 4);
  int* row_ptr = (int*)take((size_t)(N + 1) * 4);
  int* cursor = (int*)take((size_t)N * 4);
  int* col_src = (int*)take((size_t)E * 4);
  int* blk_sums = (int*)take(4096 * 4);

  int NB = (N + 1023) / 1024;

  wt_k<<<256, TPB, 0, stream>>>(W1, Wt1);
  wt_k<<<256, TPB, 0, stream>>>(W2, Wt2);
  wot_k<<<64, TPB, 0, stream>>>(Wo, Wot);
  zero_cnt_k<<<(N + TPB - 1) / TPB, TPB, 0, stream>>>(cnt, N);
  count_k<<<(E + TPB - 1) / TPB, TPB, 0, stream>>>(dstv, cnt, E);
  scan1_k<<<NB, TPB, 0, stream>>>(cnt, row_ptr, blk_sums, N);
  scan2_k<<<1, TPB, 0, stream>>>(blk_sums, NB);
  finalize_k<<<(N + TPB - 1) / TPB, TPB, 0, stream>>>(row_ptr, blk_sums, cursor, cnt, dis, N, E);
  fill_k<<<(E + TPB - 1) / TPB, TPB, 0, stream>>>(srcv, dstv, cursor, col_src, E);

  // GEMM grid: 8 XCD slots x 2 n-halves x ceil(nyb/8) row-chunks
  const int nyb = (N + 127) / 128;
  const int gblocks = 8 * 2 * ((nyb + 7) / 8);

  // layer 1 (reads f32 x directly, outputs dis-scaled H')
  gemm_bf16_t<true><<<gblocks, TPB, 0, stream>>>((const void*)x, Wt1, hbuf1, dis, N, nyb);
  aggregate_bf_k<<<(N + 3) / 4, TPB, 0, stream>>>(hbuf1, hbuf2, row_ptr, col_src, dis, b1, N);
  // layer 2
  gemm_bf16_t<false><<<gblocks, TPB, 0, stream>>>((const void*)hbuf2, Wt2, hbuf1, dis, N, nyb);
  aggregate_bf_k<<<(N + 3) / 4, TPB, 0, stream>>>(hbuf1, hbuf2, row_ptr, col_src, dis, b2, N);
  // output layer + fused log_softmax
  outgemm_k<<<(N + 127) / 128, TPB, 0, stream>>>(hbuf2, Wot, bo, out, N);
}